// Round 1
// baseline (10310.204 us; speedup 1.0000x reference)
//
#include <hip/hip_runtime.h>
#include <math.h>

// ---------------- problem constants ----------------
constexpr int Bn     = 16;
constexpr int NPG    = 1024;
constexpr int Nn     = Bn * NPG;     // 16384 nodes
constexpr int FIN    = 128;
constexpr int FOUT   = 256;
constexpr int CCAT   = 384;
constexpr int STEPS  = 6;
constexpr int NE     = 262144;

// ---------------- kernels ----------------

// h[n][k] = k<128 ? features[n][k] : 0
__global__ void pad_h(const float* __restrict__ f, float* __restrict__ h) {
    int i = blockIdx.x * 256 + threadIdx.x;
    int k = i & 255, n = i >> 8;
    h[i] = (k < FIN) ? f[(size_t)n * FIN + k] : 0.f;
}

// C[M,Ncol] = A[M,K] @ W[Ncol,K]^T + bias[Ncol]; M,Ncol,K multiples of 64/64/16
__global__ __launch_bounds__(256) void gemm_bt(
    const float* __restrict__ A, const float* __restrict__ W,
    const float* __restrict__ bias, float* __restrict__ C,
    int M, int Ncol, int K) {
    __shared__ float As[16][65];
    __shared__ float Ws[16][65];
    const int t  = threadIdx.x;
    const int tx = t & 15, ty = t >> 4;
    const int lr = t >> 2;           // 0..63
    const int lc = (t & 3) << 2;     // 0,4,8,12
    const float* Ag = A + (size_t)(blockIdx.y * 64 + lr) * K + lc;
    const float* Wg = W + (size_t)(blockIdx.x * 64 + lr) * K + lc;
    float acc[4][4] = {};
    for (int k0 = 0; k0 < K; k0 += 16) {
        const float4 av = *(const float4*)(Ag + k0);
        const float4 wv = *(const float4*)(Wg + k0);
        __syncthreads();
        As[lc + 0][lr] = av.x; As[lc + 1][lr] = av.y;
        As[lc + 2][lr] = av.z; As[lc + 3][lr] = av.w;
        Ws[lc + 0][lr] = wv.x; Ws[lc + 1][lr] = wv.y;
        Ws[lc + 2][lr] = wv.z; Ws[lc + 3][lr] = wv.w;
        __syncthreads();
#pragma unroll
        for (int kk = 0; kk < 16; ++kk) {
            float a[4], w[4];
#pragma unroll
            for (int i = 0; i < 4; ++i) a[i] = As[kk][ty * 4 + i];
#pragma unroll
            for (int j = 0; j < 4; ++j) w[j] = Ws[kk][tx * 4 + j];
#pragma unroll
            for (int i = 0; i < 4; ++i)
#pragma unroll
                for (int j = 0; j < 4; ++j) acc[i][j] += a[i] * w[j];
        }
    }
    const int row0 = blockIdx.y * 64 + ty * 4;
    const int col0 = blockIdx.x * 64 + tx * 4;
#pragma unroll
    for (int i = 0; i < 4; ++i)
#pragma unroll
        for (int j = 0; j < 4; ++j)
            C[(size_t)(row0 + i) * Ncol + col0 + j] = acc[i][j] + bias[col0 + j];
}

// agg[dst[e]][k] += Wh[etype[e]][src[e]][k]
__global__ void scatter_add(const float* __restrict__ Wh, const int* __restrict__ src,
                            const int* __restrict__ dst, const int* __restrict__ et,
                            float* __restrict__ agg) {
    int e = blockIdx.x, k = threadIdx.x;
    int s = src[e], d = dst[e], ty = et[e];
    atomicAdd(agg + (size_t)d * FOUT + k, Wh[((size_t)ty * Nn + s) * FOUT + k]);
}

// GRU cell update, in-place h
__global__ void gru_update(const float* __restrict__ gi, const float* __restrict__ gh,
                           float* __restrict__ h) {
    int i = blockIdx.x * 256 + threadIdx.x;
    int n = i >> 8, k = i & 255;
    size_t base = (size_t)n * 768;
    float ir = gi[base + k], iz = gi[base + 256 + k], ig = gi[base + 512 + k];
    float hr = gh[base + k], hz = gh[base + 256 + k], hg = gh[base + 512 + k];
    float r  = 1.f / (1.f + expf(-(ir + hr)));
    float z  = 1.f / (1.f + expf(-(iz + hz)));
    float nn = tanhf(ig + r * hg);
    h[i] = (1.f - z) * nn + z * h[i];
}

// hT[b][c][l] = h[b*NPG+l][c]
__global__ void transpose_hT(const float* __restrict__ h, float* __restrict__ hT) {
    int o = blockIdx.x * 256 + threadIdx.x;
    int l = o & 1023, c = (o >> 10) & 255, b = o >> 18;
    hT[o] = h[((size_t)(b * NPG + l)) * FOUT + c];
}

// cT[b][c][l] = c<256 ? h[...] : features[...]
__global__ void build_cT(const float* __restrict__ h, const float* __restrict__ f,
                         float* __restrict__ cT) {
    int o = blockIdx.x * 256 + threadIdx.x;
    int l = o & 1023, c = (o >> 10) % CCAT, b = o / (CCAT * NPG);
    int node = b * NPG + l;
    cT[o] = (c < FOUT) ? h[(size_t)node * FOUT + c]
                       : f[(size_t)node * FIN + (c - FOUT)];
}

// y[b][c][l] = bias[c] + sum_i sum_{k<3} W[c][i][k] * X[b][i][l+k]
__global__ void conv1d_k3(const float* __restrict__ X, const float* __restrict__ W,
                          const float* __restrict__ bias, float* __restrict__ Y,
                          int C, int Lin) {
    const int Lout = Lin - 2;
    const int b = blockIdx.y, l = blockIdx.x, c = threadIdx.x;
    extern __shared__ float xs[];
    const float* xb = X + (size_t)b * C * Lin;
#pragma unroll
    for (int k = 0; k < 3; ++k) xs[k * C + c] = xb[(size_t)c * Lin + l + k];
    __syncthreads();
    float acc = bias[c];
    const float* w = W + (size_t)c * C * 3;
#pragma unroll 4
    for (int i = 0; i < C; ++i)
        acc += w[i * 3 + 0] * xs[i] + w[i * 3 + 1] * xs[C + i] + w[i * 3 + 2] * xs[2 * C + i];
    Y[((size_t)b * C + c) * Lout + l] = acc;
}

// k=1 conv
__global__ void conv1d_k1(const float* __restrict__ X, const float* __restrict__ W,
                          const float* __restrict__ bias, float* __restrict__ Y,
                          int C, int L) {
    const int b = blockIdx.y, l = blockIdx.x, c = threadIdx.x;
    extern __shared__ float xs[];
    xs[c] = X[((size_t)b * C + c) * L + l];
    __syncthreads();
    float acc = bias[c];
    const float* w = W + (size_t)c * C;
#pragma unroll 4
    for (int i = 0; i < C; ++i) acc += w[i] * xs[i];
    Y[((size_t)b * C + c) * L + l] = acc;
}

// per-channel batch stats over (B, L), biased var
__global__ void bn_stats(const float* __restrict__ Y, float* __restrict__ mean,
                         float* __restrict__ var, int C, int L) {
    const int c = blockIdx.x, t = threadIdx.x;
    const int total = Bn * L;
    float s = 0.f, q = 0.f;
    for (int idx = t; idx < total; idx += 256) {
        int b = idx / L, l = idx - b * L;
        float v = Y[((size_t)b * C + c) * L + l];
        s += v; q += v * v;
    }
    __shared__ float rs[256], rq[256];
    rs[t] = s; rq[t] = q;
    __syncthreads();
    for (int st = 128; st; st >>= 1) {
        if (t < st) { rs[t] += rs[t + st]; rq[t] += rq[t + st]; }
        __syncthreads();
    }
    if (t == 0) {
        float m = rs[0] / total;
        mean[c] = m;
        var[c]  = rq[0] / total - m * m;
    }
}

// fused BN(affine) + ReLU + maxpool(Kp, Sp)
__global__ void bn_relu_pool(const float* __restrict__ Y, const float* __restrict__ mean,
                             const float* __restrict__ var, const float* __restrict__ g,
                             const float* __restrict__ bta, float* __restrict__ O,
                             int C, int Lin, int Lout, int Kp, int Sp) {
    int o = blockIdx.x * 256 + threadIdx.x;
    if (o >= Bn * C * Lout) return;
    int j = o % Lout, c = (o / Lout) % C, b = o / (Lout * C);
    float sc = g[c] * rsqrtf(var[c] + 1e-5f);
    float sh = bta[c] - mean[c] * sc;
    const float* yrow = Y + ((size_t)b * C + c) * Lin + (size_t)j * Sp;
    float m = -1e30f;
    for (int k = 0; k < Kp; ++k) {
        float v = fmaxf(yrow[k] * sc + sh, 0.f);
        m = fmaxf(m, v);
    }
    O[((size_t)b * C + c) * Lout + j] = m;
}

// prod[b][j][o] = (Y2[b][:,j]·wy[o] + by[o]) * (Z2[b][:,j]·wz[o] + bz[o])
__global__ void final_dot(const float* __restrict__ Y2, const float* __restrict__ Z2,
                          const float* __restrict__ wy, const float* __restrict__ by,
                          const float* __restrict__ wz, const float* __restrict__ bz,
                          float* __restrict__ prod) {
    const int b = blockIdx.y, j = blockIdx.x, t = threadIdx.x;  // 128 threads
    float p0 = 0, p1 = 0, q0 = 0, q1 = 0;
    for (int c = t; c < FOUT; c += 128) {
        float v = Y2[((size_t)b * FOUT + c) * 255 + j];
        p0 += v * wy[c]; p1 += v * wy[FOUT + c];
    }
    for (int c = t; c < CCAT; c += 128) {
        float v = Z2[((size_t)b * CCAT + c) * 255 + j];
        q0 += v * wz[c]; q1 += v * wz[CCAT + c];
    }
    __shared__ float r0[128], r1[128], r2[128], r3[128];
    r0[t] = p0; r1[t] = p1; r2[t] = q0; r3[t] = q1;
    __syncthreads();
    for (int s = 64; s; s >>= 1) {
        if (t < s) { r0[t] += r0[t + s]; r1[t] += r1[t + s]; r2[t] += r2[t + s]; r3[t] += r3[t + s]; }
        __syncthreads();
    }
    if (t == 0) {
        float y0 = r0[0] + by[0], y1 = r1[0] + by[1];
        float z0 = r2[0] + bz[0], z1 = r3[0] + bz[1];
        prod[((size_t)b * 255 + j) * 2 + 0] = y0 * z0;
        prod[((size_t)b * 255 + j) * 2 + 1] = y1 * z1;
    }
}

// out[b][o] = sigmoid(mean_j prod[b][j][o])
__global__ void final_out(const float* __restrict__ prod, float* __restrict__ out) {
    const int b = blockIdx.x, t = threadIdx.x;   // 128 threads = 2 waves
    const int w = t >> 6, lane = t & 63;
    float s = 0.f;
    for (int j = lane; j < 255; j += 64) s += prod[((size_t)b * 255 + j) * 2 + w];
#pragma unroll
    for (int off = 32; off; off >>= 1) s += __shfl_down(s, off);
    if (lane == 0) out[b * 2 + w] = 1.f / (1.f + expf(-s / 255.f));
}

// ---------------- launch ----------------
extern "C" void kernel_launch(void* const* d_in, const int* in_sizes, int n_in,
                              void* d_out, int out_size, void* d_ws, size_t ws_size,
                              hipStream_t stream) {
    (void)in_sizes; (void)n_in; (void)out_size; (void)ws_size;
    const float* features = (const float*)d_in[0];
    const int*   src      = (const int*)d_in[1];
    const int*   dst      = (const int*)d_in[2];
    const int*   etype    = (const int*)d_in[3];
    const float* W_lin    = (const float*)d_in[4];
    const float* b_lin    = (const float*)d_in[5];
    const float* W_ih     = (const float*)d_in[6];
    const float* W_hh     = (const float*)d_in[7];
    const float* b_ih     = (const float*)d_in[8];
    const float* b_hh     = (const float*)d_in[9];
    const float* conv1_w  = (const float*)d_in[10];
    const float* conv1_b  = (const float*)d_in[11];
    const float* conv2_w  = (const float*)d_in[12];
    const float* conv2_b  = (const float*)d_in[13];
    const float* convc1_w = (const float*)d_in[14];
    const float* convc1_b = (const float*)d_in[15];
    const float* convc2_w = (const float*)d_in[16];
    const float* convc2_b = (const float*)d_in[17];
    const float* bn_g     = (const float*)d_in[18];
    const float* bn_b     = (const float*)d_in[19];
    const float* bnc_g    = (const float*)d_in[20];
    const float* bnc_b    = (const float*)d_in[21];
    const float* mlpy_w   = (const float*)d_in[22];
    const float* mlpy_b   = (const float*)d_in[23];
    const float* mlpz_w   = (const float*)d_in[24];
    const float* mlpz_b   = (const float*)d_in[25];

    float* ws   = (float*)d_ws;
    float* h    = ws;                       // 4,194,304 floats
    float* agg  = ws + 4194304;             // 4,194,304
    float* bufA = ws + 8388608;             // 12,582,912  (Wh -> gi ; conv Y scratch)
    float* bufB = ws + 20971520;            // 12,582,912  (gh ; conv Z scratch)
    float* sreg = ws + 33554432;            // stats + prod

    // ---- GGNN ----
    pad_h<<<Nn * FOUT / 256, 256, 0, stream>>>(features, h);

    for (int s6 = 0; s6 < STEPS; ++s6) {
        for (int e = 0; e < 2; ++e)
            gemm_bt<<<dim3(FOUT / 64, Nn / 64), 256, 0, stream>>>(
                h, W_lin + (size_t)e * FOUT * FOUT, b_lin + e * FOUT,
                bufA + (size_t)e * Nn * FOUT, Nn, FOUT, FOUT);
        hipMemsetAsync(agg, 0, (size_t)Nn * FOUT * sizeof(float), stream);
        scatter_add<<<NE, FOUT, 0, stream>>>(bufA, src, dst, etype, agg);
        // gh (reads h) into bufB, then gi (reads agg) overwrites Wh in bufA
        gemm_bt<<<dim3(768 / 64, Nn / 64), 256, 0, stream>>>(h, W_hh, b_hh, bufB, Nn, 768, FOUT);
        gemm_bt<<<dim3(768 / 64, Nn / 64), 256, 0, stream>>>(agg, W_ih, b_ih, bufA, Nn, 768, FOUT);
        gru_update<<<Nn * FOUT / 256, 256, 0, stream>>>(bufA, bufB, h);
    }

    // ---- conv phase scratch layout ----
    float* hT    = agg;                  // [16][256][1024]
    float* cT    = bufB;                 // [16][384][1024]
    float* Ybuf  = bufA;                 // [16][256][1022]
    float* Y1p   = bufA + 4186112;       // [16][256][510]
    float* Y2buf = bufA + 6275072;       // [16][256][510]
    float* Y2    = bufA + 8364032;       // [16][256][255]
    float* Zbuf  = bufB + 6291456;       // [16][384][1022]
    float* Z1p   = bufB;                 // [16][384][510]  (over dead cT)
    float* Z2buf = bufB + 3133440;       // [16][384][510]
    float* Z2    = bufB + 6291456;       // [16][384][255]  (over dead Zbuf)
    float* meanb = sreg;
    float* varb  = sreg + 384;
    float* prod  = sreg + 768;           // [16][255][2]

    transpose_hT<<<Bn * FOUT * NPG / 256, 256, 0, stream>>>(h, hT);
    build_cT<<<Bn * CCAT * NPG / 256, 256, 0, stream>>>(h, features, cT);

    // Y branch
    conv1d_k3<<<dim3(1022, Bn), FOUT, 3 * FOUT * 4, stream>>>(hT, conv1_w, conv1_b, Ybuf, FOUT, 1024);
    bn_stats<<<FOUT, 256, 0, stream>>>(Ybuf, meanb, varb, FOUT, 1022);
    bn_relu_pool<<<(Bn * FOUT * 510 + 255) / 256, 256, 0, stream>>>(
        Ybuf, meanb, varb, bn_g, bn_b, Y1p, FOUT, 1022, 510, 3, 2);
    conv1d_k1<<<dim3(510, Bn), FOUT, FOUT * 4, stream>>>(Y1p, conv2_w, conv2_b, Y2buf, FOUT, 510);
    bn_stats<<<FOUT, 256, 0, stream>>>(Y2buf, meanb, varb, FOUT, 510);
    bn_relu_pool<<<(Bn * FOUT * 255 + 255) / 256, 256, 0, stream>>>(
        Y2buf, meanb, varb, bn_g, bn_b, Y2, FOUT, 510, 255, 2, 2);

    // Z branch
    conv1d_k3<<<dim3(1022, Bn), CCAT, 3 * CCAT * 4, stream>>>(cT, convc1_w, convc1_b, Zbuf, CCAT, 1024);
    bn_stats<<<CCAT, 256, 0, stream>>>(Zbuf, meanb, varb, CCAT, 1022);
    bn_relu_pool<<<(Bn * CCAT * 510 + 255) / 256, 256, 0, stream>>>(
        Zbuf, meanb, varb, bnc_g, bnc_b, Z1p, CCAT, 1022, 510, 3, 2);
    conv1d_k1<<<dim3(510, Bn), CCAT, CCAT * 4, stream>>>(Z1p, convc2_w, convc2_b, Z2buf, CCAT, 510);
    bn_stats<<<CCAT, 256, 0, stream>>>(Z2buf, meanb, varb, CCAT, 510);
    bn_relu_pool<<<(Bn * CCAT * 255 + 255) / 256, 256, 0, stream>>>(
        Z2buf, meanb, varb, bnc_g, bnc_b, Z2, CCAT, 510, 255, 2, 2);

    // gating + mean + sigmoid
    final_dot<<<dim3(255, Bn), 128, 0, stream>>>(Y2, Z2, mlpy_w, mlpy_b, mlpz_w, mlpz_b, prod);
    final_out<<<Bn, 128, 0, stream>>>(prod, (float*)d_out);
}

// Round 2
// 4056.590 us; speedup vs baseline: 2.5416x; 2.5416x over previous
//
#include <hip/hip_runtime.h>
#include <math.h>

// ---------------- problem constants ----------------
constexpr int Bn     = 16;
constexpr int NPG    = 1024;
constexpr int Nn     = Bn * NPG;     // 16384 nodes
constexpr int FIN    = 128;
constexpr int FOUT   = 256;
constexpr int CCAT   = 384;
constexpr int STEPS  = 6;
constexpr int NE     = 262144;

// ---------------- kernels ----------------

// h[n][k] = k<128 ? features[n][k] : 0
__global__ void pad_h(const float* __restrict__ f, float* __restrict__ h) {
    int i = blockIdx.x * 256 + threadIdx.x;
    int k = i & 255, n = i >> 8;
    h[i] = (k < FIN) ? f[(size_t)n * FIN + k] : 0.f;
}

// C[M,Ncol] = A[M,K] @ W[Ncol,K]^T + bias[Ncol]; M,Ncol,K multiples of 64/64/16
__global__ __launch_bounds__(256) void gemm_bt(
    const float* __restrict__ A, const float* __restrict__ W,
    const float* __restrict__ bias, float* __restrict__ C,
    int M, int Ncol, int K) {
    __shared__ float As[16][65];
    __shared__ float Ws[16][65];
    const int t  = threadIdx.x;
    const int tx = t & 15, ty = t >> 4;
    const int lr = t >> 2;           // 0..63
    const int lc = (t & 3) << 2;     // 0,4,8,12
    const float* Ag = A + (size_t)(blockIdx.y * 64 + lr) * K + lc;
    const float* Wg = W + (size_t)(blockIdx.x * 64 + lr) * K + lc;
    float acc[4][4] = {};
    for (int k0 = 0; k0 < K; k0 += 16) {
        const float4 av = *(const float4*)(Ag + k0);
        const float4 wv = *(const float4*)(Wg + k0);
        __syncthreads();
        As[lc + 0][lr] = av.x; As[lc + 1][lr] = av.y;
        As[lc + 2][lr] = av.z; As[lc + 3][lr] = av.w;
        Ws[lc + 0][lr] = wv.x; Ws[lc + 1][lr] = wv.y;
        Ws[lc + 2][lr] = wv.z; Ws[lc + 3][lr] = wv.w;
        __syncthreads();
#pragma unroll
        for (int kk = 0; kk < 16; ++kk) {
            float a[4], w[4];
#pragma unroll
            for (int i = 0; i < 4; ++i) a[i] = As[kk][ty * 4 + i];
#pragma unroll
            for (int j = 0; j < 4; ++j) w[j] = Ws[kk][tx * 4 + j];
#pragma unroll
            for (int i = 0; i < 4; ++i)
#pragma unroll
                for (int j = 0; j < 4; ++j) acc[i][j] += a[i] * w[j];
        }
    }
    const int row0 = blockIdx.y * 64 + ty * 4;
    const int col0 = blockIdx.x * 64 + tx * 4;
#pragma unroll
    for (int i = 0; i < 4; ++i)
#pragma unroll
        for (int j = 0; j < 4; ++j)
            C[(size_t)(row0 + i) * Ncol + col0 + j] = acc[i][j] + bias[col0 + j];
}

// agg[dst[e]][k] += Wh[etype[e]][src[e]][k]
__global__ void scatter_add(const float* __restrict__ Wh, const int* __restrict__ src,
                            const int* __restrict__ dst, const int* __restrict__ et,
                            float* __restrict__ agg) {
    int e = blockIdx.x, k = threadIdx.x;
    int s = src[e], d = dst[e], ty = et[e];
    atomicAdd(agg + (size_t)d * FOUT + k, Wh[((size_t)ty * Nn + s) * FOUT + k]);
}

// GRU cell update, in-place h
__global__ void gru_update(const float* __restrict__ gi, const float* __restrict__ gh,
                           float* __restrict__ h) {
    int i = blockIdx.x * 256 + threadIdx.x;
    int n = i >> 8, k = i & 255;
    size_t base = (size_t)n * 768;
    float ir = gi[base + k], iz = gi[base + 256 + k], ig = gi[base + 512 + k];
    float hr = gh[base + k], hz = gh[base + 256 + k], hg = gh[base + 512 + k];
    float r  = 1.f / (1.f + expf(-(ir + hr)));
    float z  = 1.f / (1.f + expf(-(iz + hz)));
    float nn = tanhf(ig + r * hg);
    h[i] = (1.f - z) * nn + z * h[i];
}

// hT[b][c][l] = h[b*NPG+l][c]
__global__ void transpose_hT(const float* __restrict__ h, float* __restrict__ hT) {
    int o = blockIdx.x * 256 + threadIdx.x;
    int l = o & 1023, c = (o >> 10) & 255, b = o >> 18;
    hT[o] = h[((size_t)(b * NPG + l)) * FOUT + c];
}

// cT[b][c][l] = c<256 ? h[...] : features[...]
__global__ void build_cT(const float* __restrict__ h, const float* __restrict__ f,
                         float* __restrict__ cT) {
    int o = blockIdx.x * 256 + threadIdx.x;
    int l = o & 1023, c = (o >> 10) % CCAT, b = o / (CCAT * NPG);
    int node = b * NPG + l;
    cT[o] = (c < FOUT) ? h[(size_t)node * FOUT + c]
                       : f[(size_t)node * FIN + (c - FOUT)];
}

// Tiled implicit-GEMM conv1d, kernel width KW (1 or 3), VALID padding.
// X: [B][C][Lin], W: [C][C][KW], Y: [B][C][Lout], Lout = Lin - KW + 1.
// Block: 256 threads -> 64 out-channels x 64 positions; K-loop over in-channels (16/iter).
template<int KW>
__global__ __launch_bounds__(256) void conv_tiled(
    const float* __restrict__ X, const float* __restrict__ W,
    const float* __restrict__ bias, float* __restrict__ Y,
    int C, int Lin, int Lout) {
    constexpr int WS = KW * 16 + 1;          // Ws row stride (pad: banks differ across ty)
    __shared__ float Xs[16][68];             // 68 -> 16B-aligned rows for b128 reads
    __shared__ float Ws[64][WS];

    const int t   = threadIdx.x;
    const int tx  = t & 15, ty = t >> 4;     // tx: l-group, ty: c-group
    const int tx4 = tx * 4, ty4 = ty * 4;
    const int b   = blockIdx.z;
    const int l0  = blockIdx.x * 64;
    const int c0  = blockIdx.y * 64;

    // X-load lane mapping: 16 rows x 16 quads
    const int xr = t >> 4, xq = t & 15;
    // W-load lane mapping: 4 threads per out-channel row
    const int wr = t >> 2, wq = t & 3;

    float acc[4][4] = {};

    for (int i0 = 0; i0 < C; i0 += 16) {
        __syncthreads();
        // ---- stage X[i0..i0+15][l0..l0+63+KW-1] ----
        {
            const float* xrow = X + ((size_t)b * C + i0 + xr) * Lin + l0;
            const int g = xq * 4;
            float v0, v1, v2, v3;
            if (KW == 3) {                    // Lin=1024: rows 16B-aligned -> float4 ok
                if (l0 + g + 3 < Lin) {
                    float4 xv = *(const float4*)(xrow + g);
                    v0 = xv.x; v1 = xv.y; v2 = xv.z; v3 = xv.w;
                } else {
                    v0 = (l0 + g + 0 < Lin) ? xrow[g + 0] : 0.f;
                    v1 = (l0 + g + 1 < Lin) ? xrow[g + 1] : 0.f;
                    v2 = (l0 + g + 2 < Lin) ? xrow[g + 2] : 0.f;
                    v3 = (l0 + g + 3 < Lin) ? xrow[g + 3] : 0.f;
                }
            } else {                          // Lin=510: rows only 8B-aligned -> float2s
                if (l0 + g + 1 < Lin) {
                    float2 xv = *(const float2*)(xrow + g);
                    v0 = xv.x; v1 = xv.y;
                } else {
                    v0 = (l0 + g + 0 < Lin) ? xrow[g + 0] : 0.f;
                    v1 = (l0 + g + 1 < Lin) ? xrow[g + 1] : 0.f;
                }
                if (l0 + g + 3 < Lin) {
                    float2 xv = *(const float2*)(xrow + g + 2);
                    v2 = xv.x; v3 = xv.y;
                } else {
                    v2 = (l0 + g + 2 < Lin) ? xrow[g + 2] : 0.f;
                    v3 = (l0 + g + 3 < Lin) ? xrow[g + 3] : 0.f;
                }
            }
            Xs[xr][g + 0] = v0; Xs[xr][g + 1] = v1;
            Xs[xr][g + 2] = v2; Xs[xr][g + 3] = v3;
            if (KW == 3 && xq == 0) {        // halo cols 64,65
#pragma unroll
                for (int j = 0; j < 2; ++j)
                    Xs[xr][64 + j] = (l0 + 64 + j < Lin) ? xrow[64 + j] : 0.f;
            }
        }
        // ---- stage W[c0..c0+63][i0..i0+15][0..KW-1] (contiguous KW*16 floats/row) ----
        {
            const float* wrow = W + ((size_t)(c0 + wr) * C + i0) * KW + wq * KW * 4;
#pragma unroll
            for (int u = 0; u < KW; ++u) {
                float4 wv = *(const float4*)(wrow + u * 4);
                const int o = wq * KW * 4 + u * 4;
                Ws[wr][o + 0] = wv.x; Ws[wr][o + 1] = wv.y;
                Ws[wr][o + 2] = wv.z; Ws[wr][o + 3] = wv.w;
            }
        }
        __syncthreads();
        // ---- compute ----
#pragma unroll
        for (int kk = 0; kk < 16; ++kk) {
            float xv[4 + KW - 1];
            {
                float4 x0 = *(const float4*)&Xs[kk][tx4];
                xv[0] = x0.x; xv[1] = x0.y; xv[2] = x0.z; xv[3] = x0.w;
                if (KW == 3) {
                    float2 x1 = *(const float2*)&Xs[kk][tx4 + 4];
                    xv[4] = x1.x; xv[5] = x1.y;
                }
            }
#pragma unroll
            for (int ci = 0; ci < 4; ++ci) {
#pragma unroll
                for (int k = 0; k < KW; ++k) {
                    float wv = Ws[ty4 + ci][kk * KW + k];
#pragma unroll
                    for (int lj = 0; lj < 4; ++lj)
                        acc[ci][lj] += wv * xv[lj + k];
                }
            }
        }
    }
    // ---- store (+bias); rows are 8B-aligned (Lout even) -> float2 pairs ----
    const int ow = l0 + tx4;
#pragma unroll
    for (int ci = 0; ci < 4; ++ci) {
        const int c = c0 + ty4 + ci;
        float* yrow = Y + ((size_t)b * C + c) * Lout;
        const float bv = bias[c];
        if (ow + 3 < Lout) {
            float2 s0 = make_float2(acc[ci][0] + bv, acc[ci][1] + bv);
            float2 s1 = make_float2(acc[ci][2] + bv, acc[ci][3] + bv);
            *(float2*)(yrow + ow) = s0;
            *(float2*)(yrow + ow + 2) = s1;
        } else {
#pragma unroll
            for (int lj = 0; lj < 4; ++lj)
                if (ow + lj < Lout) yrow[ow + lj] = acc[ci][lj] + bv;
        }
    }
}

// per-channel batch stats over (B, L), biased var
__global__ void bn_stats(const float* __restrict__ Y, float* __restrict__ mean,
                         float* __restrict__ var, int C, int L) {
    const int c = blockIdx.x, t = threadIdx.x;
    const int total = Bn * L;
    float s = 0.f, q = 0.f;
    for (int idx = t; idx < total; idx += 256) {
        int b = idx / L, l = idx - b * L;
        float v = Y[((size_t)b * C + c) * L + l];
        s += v; q += v * v;
    }
    __shared__ float rs[256], rq[256];
    rs[t] = s; rq[t] = q;
    __syncthreads();
    for (int st = 128; st; st >>= 1) {
        if (t < st) { rs[t] += rs[t + st]; rq[t] += rq[t + st]; }
        __syncthreads();
    }
    if (t == 0) {
        float m = rs[0] / total;
        mean[c] = m;
        var[c]  = rq[0] / total - m * m;
    }
}

// fused BN(affine) + ReLU + maxpool(Kp, Sp)
__global__ void bn_relu_pool(const float* __restrict__ Y, const float* __restrict__ mean,
                             const float* __restrict__ var, const float* __restrict__ g,
                             const float* __restrict__ bta, float* __restrict__ O,
                             int C, int Lin, int Lout, int Kp, int Sp) {
    int o = blockIdx.x * 256 + threadIdx.x;
    if (o >= Bn * C * Lout) return;
    int j = o % Lout, c = (o / Lout) % C, b = o / (Lout * C);
    float sc = g[c] * rsqrtf(var[c] + 1e-5f);
    float sh = bta[c] - mean[c] * sc;
    const float* yrow = Y + ((size_t)b * C + c) * Lin + (size_t)j * Sp;
    float m = -1e30f;
    for (int k = 0; k < Kp; ++k) {
        float v = fmaxf(yrow[k] * sc + sh, 0.f);
        m = fmaxf(m, v);
    }
    O[((size_t)b * C + c) * Lout + j] = m;
}

// prod[b][j][o] = (Y2[b][:,j]·wy[o] + by[o]) * (Z2[b][:,j]·wz[o] + bz[o])
__global__ void final_dot(const float* __restrict__ Y2, const float* __restrict__ Z2,
                          const float* __restrict__ wy, const float* __restrict__ by,
                          const float* __restrict__ wz, const float* __restrict__ bz,
                          float* __restrict__ prod) {
    const int b = blockIdx.y, j = blockIdx.x, t = threadIdx.x;  // 128 threads
    float p0 = 0, p1 = 0, q0 = 0, q1 = 0;
    for (int c = t; c < FOUT; c += 128) {
        float v = Y2[((size_t)b * FOUT + c) * 255 + j];
        p0 += v * wy[c]; p1 += v * wy[FOUT + c];
    }
    for (int c = t; c < CCAT; c += 128) {
        float v = Z2[((size_t)b * CCAT + c) * 255 + j];
        q0 += v * wz[c]; q1 += v * wz[CCAT + c];
    }
    __shared__ float r0[128], r1[128], r2[128], r3[128];
    r0[t] = p0; r1[t] = p1; r2[t] = q0; r3[t] = q1;
    __syncthreads();
    for (int s = 64; s; s >>= 1) {
        if (t < s) { r0[t] += r0[t + s]; r1[t] += r1[t + s]; r2[t] += r2[t + s]; r3[t] += r3[t + s]; }
        __syncthreads();
    }
    if (t == 0) {
        float y0 = r0[0] + by[0], y1 = r1[0] + by[1];
        float z0 = r2[0] + bz[0], z1 = r3[0] + bz[1];
        prod[((size_t)b * 255 + j) * 2 + 0] = y0 * z0;
        prod[((size_t)b * 255 + j) * 2 + 1] = y1 * z1;
    }
}

// out[b][o] = sigmoid(mean_j prod[b][j][o])
__global__ void final_out(const float* __restrict__ prod, float* __restrict__ out) {
    const int b = blockIdx.x, t = threadIdx.x;   // 128 threads = 2 waves
    const int w = t >> 6, lane = t & 63;
    float s = 0.f;
    for (int j = lane; j < 255; j += 64) s += prod[((size_t)b * 255 + j) * 2 + w];
#pragma unroll
    for (int off = 32; off; off >>= 1) s += __shfl_down(s, off);
    if (lane == 0) out[b * 2 + w] = 1.f / (1.f + expf(-s / 255.f));
}

// ---------------- launch ----------------
extern "C" void kernel_launch(void* const* d_in, const int* in_sizes, int n_in,
                              void* d_out, int out_size, void* d_ws, size_t ws_size,
                              hipStream_t stream) {
    (void)in_sizes; (void)n_in; (void)out_size; (void)ws_size;
    const float* features = (const float*)d_in[0];
    const int*   src      = (const int*)d_in[1];
    const int*   dst      = (const int*)d_in[2];
    const int*   etype    = (const int*)d_in[3];
    const float* W_lin    = (const float*)d_in[4];
    const float* b_lin    = (const float*)d_in[5];
    const float* W_ih     = (const float*)d_in[6];
    const float* W_hh     = (const float*)d_in[7];
    const float* b_ih     = (const float*)d_in[8];
    const float* b_hh     = (const float*)d_in[9];
    const float* conv1_w  = (const float*)d_in[10];
    const float* conv1_b  = (const float*)d_in[11];
    const float* conv2_w  = (const float*)d_in[12];
    const float* conv2_b  = (const float*)d_in[13];
    const float* convc1_w = (const float*)d_in[14];
    const float* convc1_b = (const float*)d_in[15];
    const float* convc2_w = (const float*)d_in[16];
    const float* convc2_b = (const float*)d_in[17];
    const float* bn_g     = (const float*)d_in[18];
    const float* bn_b     = (const float*)d_in[19];
    const float* bnc_g    = (const float*)d_in[20];
    const float* bnc_b    = (const float*)d_in[21];
    const float* mlpy_w   = (const float*)d_in[22];
    const float* mlpy_b   = (const float*)d_in[23];
    const float* mlpz_w   = (const float*)d_in[24];
    const float* mlpz_b   = (const float*)d_in[25];

    float* ws   = (float*)d_ws;
    float* h    = ws;                       // 4,194,304 floats
    float* agg  = ws + 4194304;             // 4,194,304
    float* bufA = ws + 8388608;             // 12,582,912  (Wh -> gi ; conv Y scratch)
    float* bufB = ws + 20971520;            // 12,582,912  (gh ; conv Z scratch)
    float* sreg = ws + 33554432;            // stats + prod

    // ---- GGNN ----
    pad_h<<<Nn * FOUT / 256, 256, 0, stream>>>(features, h);

    for (int s6 = 0; s6 < STEPS; ++s6) {
        for (int e = 0; e < 2; ++e)
            gemm_bt<<<dim3(FOUT / 64, Nn / 64), 256, 0, stream>>>(
                h, W_lin + (size_t)e * FOUT * FOUT, b_lin + e * FOUT,
                bufA + (size_t)e * Nn * FOUT, Nn, FOUT, FOUT);
        hipMemsetAsync(agg, 0, (size_t)Nn * FOUT * sizeof(float), stream);
        scatter_add<<<NE, FOUT, 0, stream>>>(bufA, src, dst, etype, agg);
        // gh (reads h) into bufB, then gi (reads agg) overwrites Wh in bufA
        gemm_bt<<<dim3(768 / 64, Nn / 64), 256, 0, stream>>>(h, W_hh, b_hh, bufB, Nn, 768, FOUT);
        gemm_bt<<<dim3(768 / 64, Nn / 64), 256, 0, stream>>>(agg, W_ih, b_ih, bufA, Nn, 768, FOUT);
        gru_update<<<Nn * FOUT / 256, 256, 0, stream>>>(bufA, bufB, h);
    }

    // ---- conv phase scratch layout ----
    float* hT    = agg;                  // [16][256][1024]
    float* cT    = bufB;                 // [16][384][1024]
    float* Ybuf  = bufA;                 // [16][256][1022]
    float* Y1p   = bufA + 4186112;       // [16][256][510]
    float* Y2buf = bufA + 6275072;       // [16][256][510]
    float* Y2    = bufA + 8364032;       // [16][256][255]
    float* Zbuf  = bufB + 6291456;       // [16][384][1022]
    float* Z1p   = bufB;                 // [16][384][510]  (over dead cT)
    float* Z2buf = bufB + 3133440;       // [16][384][510]
    float* Z2    = bufB + 6291456;       // [16][384][255]  (over dead Zbuf)
    float* meanb = sreg;
    float* varb  = sreg + 384;
    float* prod  = sreg + 768;           // [16][255][2]

    transpose_hT<<<Bn * FOUT * NPG / 256, 256, 0, stream>>>(h, hT);
    build_cT<<<Bn * CCAT * NPG / 256, 256, 0, stream>>>(h, features, cT);

    // Y branch
    conv_tiled<3><<<dim3(16, FOUT / 64, Bn), 256, 0, stream>>>(hT, conv1_w, conv1_b, Ybuf, FOUT, 1024, 1022);
    bn_stats<<<FOUT, 256, 0, stream>>>(Ybuf, meanb, varb, FOUT, 1022);
    bn_relu_pool<<<(Bn * FOUT * 510 + 255) / 256, 256, 0, stream>>>(
        Ybuf, meanb, varb, bn_g, bn_b, Y1p, FOUT, 1022, 510, 3, 2);
    conv_tiled<1><<<dim3(8, FOUT / 64, Bn), 256, 0, stream>>>(Y1p, conv2_w, conv2_b, Y2buf, FOUT, 510, 510);
    bn_stats<<<FOUT, 256, 0, stream>>>(Y2buf, meanb, varb, FOUT, 510);
    bn_relu_pool<<<(Bn * FOUT * 255 + 255) / 256, 256, 0, stream>>>(
        Y2buf, meanb, varb, bn_g, bn_b, Y2, FOUT, 510, 255, 2, 2);

    // Z branch
    conv_tiled<3><<<dim3(16, CCAT / 64, Bn), 256, 0, stream>>>(cT, convc1_w, convc1_b, Zbuf, CCAT, 1024, 1022);
    bn_stats<<<CCAT, 256, 0, stream>>>(Zbuf, meanb, varb, CCAT, 1022);
    bn_relu_pool<<<(Bn * CCAT * 510 + 255) / 256, 256, 0, stream>>>(
        Zbuf, meanb, varb, bnc_g, bnc_b, Z1p, CCAT, 1022, 510, 3, 2);
    conv_tiled<1><<<dim3(8, CCAT / 64, Bn), 256, 0, stream>>>(Z1p, convc2_w, convc2_b, Z2buf, CCAT, 510, 510);
    bn_stats<<<CCAT, 256, 0, stream>>>(Z2buf, meanb, varb, CCAT, 510);
    bn_relu_pool<<<(Bn * CCAT * 255 + 255) / 256, 256, 0, stream>>>(
        Z2buf, meanb, varb, bnc_g, bnc_b, Z2, CCAT, 510, 255, 2, 2);

    // gating + mean + sigmoid
    final_dot<<<dim3(255, Bn), 128, 0, stream>>>(Y2, Z2, mlpy_w, mlpy_b, mlpz_w, mlpz_b, prod);
    final_out<<<Bn, 128, 0, stream>>>(prod, (float*)d_out);
}

// Round 3
// 1300.915 us; speedup vs baseline: 7.9253x; 3.1183x over previous
//
#include <hip/hip_runtime.h>
#include <math.h>

// ---------------- problem constants ----------------
constexpr int Bn     = 16;
constexpr int NPG    = 1024;
constexpr int Nn     = Bn * NPG;     // 16384 nodes
constexpr int FIN    = 128;
constexpr int FOUT   = 256;
constexpr int CCAT   = 384;
constexpr int STEPS  = 6;
constexpr int NE     = 262144;

using short8 = __attribute__((ext_vector_type(8))) short;
using f32x4  = __attribute__((ext_vector_type(4))) float;

static __device__ __forceinline__ unsigned short f2bf(float x) {
    union { float f; unsigned u; } v; v.f = x;
    unsigned r = (v.u + 0x7FFFu + ((v.u >> 16) & 1u)) >> 16;
    return (unsigned short)r;
}
static __device__ __forceinline__ float bf2f(unsigned short b) {
    union { unsigned u; float f; } v; v.u = ((unsigned)b) << 16;
    return v.f;
}

// ---------------- small utility kernels ----------------

__global__ void cvt_bf(const float* __restrict__ s, unsigned short* __restrict__ d, int n) {
    int i = blockIdx.x * 256 + threadIdx.x;
    if (i < n) d[i] = f2bf(s[i]);
}

// h[n][k] = k<128 ? features[n][k] : 0 ; also bf16 copy
__global__ void pad_h(const float* __restrict__ f, float* __restrict__ h,
                      unsigned short* __restrict__ hb) {
    int i = blockIdx.x * 256 + threadIdx.x;
    int k = i & 255, n = i >> 8;
    float v = (k < FIN) ? f[(size_t)n * FIN + k] : 0.f;
    h[i] = v; hb[i] = f2bf(v);
}

// ---------------- CSR build (once per launch) ----------------

__global__ void edge_count(const int* __restrict__ dst, int* __restrict__ deg) {
    int e = blockIdx.x * 256 + threadIdx.x;
    atomicAdd(&deg[dst[e]], 1);
}

__global__ __launch_bounds__(1024) void scan_deg(const int* __restrict__ deg,
                                                 int* __restrict__ rowptr,
                                                 int* __restrict__ cursor) {
    __shared__ int ps[1024];
    const int t = threadIdx.x;
    int loc[16]; int s = 0;
    const int base = t * 16;
#pragma unroll
    for (int i = 0; i < 16; ++i) { loc[i] = deg[base + i]; s += loc[i]; }
    ps[t] = s;
    __syncthreads();
    for (int off = 1; off < 1024; off <<= 1) {
        int add = (t >= off) ? ps[t - off] : 0;
        __syncthreads();
        ps[t] += add;
        __syncthreads();
    }
    int run = ps[t] - s;  // exclusive prefix
#pragma unroll
    for (int i = 0; i < 16; ++i) { rowptr[base + i] = run; cursor[base + i] = run; run += loc[i]; }
    if (t == 1023) rowptr[16384] = run;
}

__global__ void edge_fill(const int* __restrict__ src, const int* __restrict__ dst,
                          const int* __restrict__ et, int* __restrict__ cursor,
                          int* __restrict__ widx) {
    int e = blockIdx.x * 256 + threadIdx.x;
    int slot = atomicAdd(&cursor[dst[e]], 1);
    widx[slot] = src[e] * 2 + et[e];   // row index into Wh[16384][512] grouped by 256
}

// ---------------- bf16 MFMA GEMM ----------------
// C[M,N] = A[M,256] @ W[N,256]^T + bias. A,W bf16; C fp32 or bf16.
// Block 256 thr = 4 waves; tile 128(M) x 64(N); BK=64 (4 K-iters).
__global__ __launch_bounds__(256) void gemm_mfma(
    const unsigned short* __restrict__ A, const unsigned short* __restrict__ W,
    const float* __restrict__ bias, float* __restrict__ Cf,
    unsigned short* __restrict__ Cb, int N, int outBf) {
    constexpr int K = 256;
    __shared__ unsigned short As[128][72];
    __shared__ unsigned short Bs[64][72];
    const int t = threadIdx.x;
    const int w = t >> 6, l = t & 63;
    const int lr = l & 15, lk = (l >> 4) * 8;
    const int row0 = blockIdx.y * 128, col0 = blockIdx.x * 64;
    const int sr = t >> 3, sc = (t & 7) * 8;
    f32x4 acc[2][4] = {};

    for (int k0 = 0; k0 < K; k0 += 64) {
        __syncthreads();
#pragma unroll
        for (int p = 0; p < 4; ++p) {
            int r = p * 32 + sr;
            *(uint4*)&As[r][sc] = *(const uint4*)(A + (size_t)(row0 + r) * K + k0 + sc);
        }
#pragma unroll
        for (int p = 0; p < 2; ++p) {
            int r = p * 32 + sr;
            *(uint4*)&Bs[r][sc] = *(const uint4*)(W + (size_t)(col0 + r) * K + k0 + sc);
        }
        __syncthreads();
#pragma unroll
        for (int kk = 0; kk < 2; ++kk) {
            short8 a0 = *(const short8*)&As[w * 32 + lr][kk * 32 + lk];
            short8 a1 = *(const short8*)&As[w * 32 + 16 + lr][kk * 32 + lk];
            short8 b0 = *(const short8*)&Bs[lr][kk * 32 + lk];
            short8 b1 = *(const short8*)&Bs[16 + lr][kk * 32 + lk];
            short8 b2 = *(const short8*)&Bs[32 + lr][kk * 32 + lk];
            short8 b3 = *(const short8*)&Bs[48 + lr][kk * 32 + lk];
            acc[0][0] = __builtin_amdgcn_mfma_f32_16x16x32_bf16(a0, b0, acc[0][0], 0, 0, 0);
            acc[0][1] = __builtin_amdgcn_mfma_f32_16x16x32_bf16(a0, b1, acc[0][1], 0, 0, 0);
            acc[0][2] = __builtin_amdgcn_mfma_f32_16x16x32_bf16(a0, b2, acc[0][2], 0, 0, 0);
            acc[0][3] = __builtin_amdgcn_mfma_f32_16x16x32_bf16(a0, b3, acc[0][3], 0, 0, 0);
            acc[1][0] = __builtin_amdgcn_mfma_f32_16x16x32_bf16(a1, b0, acc[1][0], 0, 0, 0);
            acc[1][1] = __builtin_amdgcn_mfma_f32_16x16x32_bf16(a1, b1, acc[1][1], 0, 0, 0);
            acc[1][2] = __builtin_amdgcn_mfma_f32_16x16x32_bf16(a1, b2, acc[1][2], 0, 0, 0);
            acc[1][3] = __builtin_amdgcn_mfma_f32_16x16x32_bf16(a1, b3, acc[1][3], 0, 0, 0);
        }
    }
    // epilogue: row = (lane>>4)*4+reg, col = lane&15  (m89-verified C/D layout)
    const int rb = (l >> 4) * 4;
#pragma unroll
    for (int i = 0; i < 2; ++i)
#pragma unroll
        for (int j = 0; j < 4; ++j) {
            const int gcol = col0 + j * 16 + lr;
            const float bv = bias[gcol];
#pragma unroll
            for (int r = 0; r < 4; ++r) {
                const int grow = row0 + w * 32 + i * 16 + rb + r;
                float v = acc[i][j][r] + bv;
                if (outBf) Cb[(size_t)grow * N + gcol] = f2bf(v);
                else       Cf[(size_t)grow * N + gcol] = v;
            }
        }
}

// ---------------- CSR gather aggregation ----------------
// aggb[n][k] = sum over in-edges of Wh[widx][k] (bf16 in, fp32 accum, bf16 out)
__global__ __launch_bounds__(64) void gather_agg(
    const unsigned short* __restrict__ Whb, const int* __restrict__ rowptr,
    const int* __restrict__ widx, unsigned short* __restrict__ aggb) {
    const int n = blockIdx.x, t = threadIdx.x;  // 64 threads, 4 ch each
    float a0 = 0, a1 = 0, a2 = 0, a3 = 0;
    const int s0 = rowptr[n], s1 = rowptr[n + 1];
    for (int s = s0; s < s1; ++s) {
        const ushort4 v = *(const ushort4*)(Whb + (size_t)widx[s] * 256 + t * 4);
        a0 += bf2f(v.x); a1 += bf2f(v.y); a2 += bf2f(v.z); a3 += bf2f(v.w);
    }
    ushort4 o; o.x = f2bf(a0); o.y = f2bf(a1); o.z = f2bf(a2); o.w = f2bf(a3);
    *(ushort4*)(aggb + (size_t)n * 256 + t * 4) = o;
}

// GRU cell update, in-place h (+ bf16 copy)
__global__ void gru_update(const float* __restrict__ gi, const float* __restrict__ gh,
                           float* __restrict__ h, unsigned short* __restrict__ hb) {
    int i = blockIdx.x * 256 + threadIdx.x;
    int n = i >> 8, k = i & 255;
    size_t base = (size_t)n * 768;
    float ir = gi[base + k], iz = gi[base + 256 + k], ig = gi[base + 512 + k];
    float hr = gh[base + k], hz = gh[base + 256 + k], hg = gh[base + 512 + k];
    float r  = 1.f / (1.f + expf(-(ir + hr)));
    float z  = 1.f / (1.f + expf(-(iz + hz)));
    float nn = tanhf(ig + r * hg);
    float hv = (1.f - z) * nn + z * h[i];
    h[i] = hv; hb[i] = f2bf(hv);
}

// hT[b][c][l] = h[b*NPG+l][c]
__global__ void transpose_hT(const float* __restrict__ h, float* __restrict__ hT) {
    int o = blockIdx.x * 256 + threadIdx.x;
    int l = o & 1023, c = (o >> 10) & 255, b = o >> 18;
    hT[o] = h[((size_t)(b * NPG + l)) * FOUT + c];
}

// cT[b][c][l] = c<256 ? h[...] : features[...]
__global__ void build_cT(const float* __restrict__ h, const float* __restrict__ f,
                         float* __restrict__ cT) {
    int o = blockIdx.x * 256 + threadIdx.x;
    int l = o & 1023, c = (o >> 10) % CCAT, b = o / (CCAT * NPG);
    int node = b * NPG + l;
    cT[o] = (c < FOUT) ? h[(size_t)node * FOUT + c]
                       : f[(size_t)node * FIN + (c - FOUT)];
}

// Tiled implicit-GEMM conv1d, kernel width KW (1 or 3), VALID padding.
template<int KW>
__global__ __launch_bounds__(256) void conv_tiled(
    const float* __restrict__ X, const float* __restrict__ W,
    const float* __restrict__ bias, float* __restrict__ Y,
    int C, int Lin, int Lout) {
    constexpr int WS = KW * 16 + 1;
    __shared__ float Xs[16][68];
    __shared__ float Ws[64][WS];

    const int t   = threadIdx.x;
    const int tx  = t & 15, ty = t >> 4;
    const int tx4 = tx * 4, ty4 = ty * 4;
    const int b   = blockIdx.z;
    const int l0  = blockIdx.x * 64;
    const int c0  = blockIdx.y * 64;

    const int xr = t >> 4, xq = t & 15;
    const int wr = t >> 2, wq = t & 3;

    float acc[4][4] = {};

    for (int i0 = 0; i0 < C; i0 += 16) {
        __syncthreads();
        {
            const float* xrow = X + ((size_t)b * C + i0 + xr) * Lin + l0;
            const int g = xq * 4;
            float v0, v1, v2, v3;
            if (KW == 3) {
                if (l0 + g + 3 < Lin) {
                    float4 xv = *(const float4*)(xrow + g);
                    v0 = xv.x; v1 = xv.y; v2 = xv.z; v3 = xv.w;
                } else {
                    v0 = (l0 + g + 0 < Lin) ? xrow[g + 0] : 0.f;
                    v1 = (l0 + g + 1 < Lin) ? xrow[g + 1] : 0.f;
                    v2 = (l0 + g + 2 < Lin) ? xrow[g + 2] : 0.f;
                    v3 = (l0 + g + 3 < Lin) ? xrow[g + 3] : 0.f;
                }
            } else {
                if (l0 + g + 1 < Lin) {
                    float2 xv = *(const float2*)(xrow + g);
                    v0 = xv.x; v1 = xv.y;
                } else {
                    v0 = (l0 + g + 0 < Lin) ? xrow[g + 0] : 0.f;
                    v1 = (l0 + g + 1 < Lin) ? xrow[g + 1] : 0.f;
                }
                if (l0 + g + 3 < Lin) {
                    float2 xv = *(const float2*)(xrow + g + 2);
                    v2 = xv.x; v3 = xv.y;
                } else {
                    v2 = (l0 + g + 2 < Lin) ? xrow[g + 2] : 0.f;
                    v3 = (l0 + g + 3 < Lin) ? xrow[g + 3] : 0.f;
                }
            }
            Xs[xr][g + 0] = v0; Xs[xr][g + 1] = v1;
            Xs[xr][g + 2] = v2; Xs[xr][g + 3] = v3;
            if (KW == 3 && xq == 0) {
#pragma unroll
                for (int j = 0; j < 2; ++j)
                    Xs[xr][64 + j] = (l0 + 64 + j < Lin) ? xrow[64 + j] : 0.f;
            }
        }
        {
            const float* wrow = W + ((size_t)(c0 + wr) * C + i0) * KW + wq * KW * 4;
#pragma unroll
            for (int u = 0; u < KW; ++u) {
                float4 wv = *(const float4*)(wrow + u * 4);
                const int o = wq * KW * 4 + u * 4;
                Ws[wr][o + 0] = wv.x; Ws[wr][o + 1] = wv.y;
                Ws[wr][o + 2] = wv.z; Ws[wr][o + 3] = wv.w;
            }
        }
        __syncthreads();
#pragma unroll
        for (int kk = 0; kk < 16; ++kk) {
            float xv[4 + KW - 1];
            {
                float4 x0 = *(const float4*)&Xs[kk][tx4];
                xv[0] = x0.x; xv[1] = x0.y; xv[2] = x0.z; xv[3] = x0.w;
                if (KW == 3) {
                    float2 x1 = *(const float2*)&Xs[kk][tx4 + 4];
                    xv[4] = x1.x; xv[5] = x1.y;
                }
            }
#pragma unroll
            for (int ci = 0; ci < 4; ++ci) {
#pragma unroll
                for (int k = 0; k < KW; ++k) {
                    float wv = Ws[ty4 + ci][kk * KW + k];
#pragma unroll
                    for (int lj = 0; lj < 4; ++lj)
                        acc[ci][lj] += wv * xv[lj + k];
                }
            }
        }
    }
    const int ow = l0 + tx4;
#pragma unroll
    for (int ci = 0; ci < 4; ++ci) {
        const int c = c0 + ty4 + ci;
        float* yrow = Y + ((size_t)b * C + c) * Lout;
        const float bv = bias[c];
        if (ow + 3 < Lout) {
            *(float2*)(yrow + ow)     = make_float2(acc[ci][0] + bv, acc[ci][1] + bv);
            *(float2*)(yrow + ow + 2) = make_float2(acc[ci][2] + bv, acc[ci][3] + bv);
        } else {
#pragma unroll
            for (int lj = 0; lj < 4; ++lj)
                if (ow + lj < Lout) yrow[ow + lj] = acc[ci][lj] + bv;
        }
    }
}

// per-channel batch stats over (B, L), biased var
__global__ void bn_stats(const float* __restrict__ Y, float* __restrict__ mean,
                         float* __restrict__ var, int C, int L) {
    const int c = blockIdx.x, t = threadIdx.x;
    const int total = Bn * L;
    float s = 0.f, q = 0.f;
    for (int idx = t; idx < total; idx += 256) {
        int b = idx / L, l = idx - b * L;
        float v = Y[((size_t)b * C + c) * L + l];
        s += v; q += v * v;
    }
    __shared__ float rs[256], rq[256];
    rs[t] = s; rq[t] = q;
    __syncthreads();
    for (int st = 128; st; st >>= 1) {
        if (t < st) { rs[t] += rs[t + st]; rq[t] += rq[t + st]; }
        __syncthreads();
    }
    if (t == 0) {
        float m = rs[0] / total;
        mean[c] = m;
        var[c]  = rq[0] / total - m * m;
    }
}

// fused BN(affine) + ReLU + maxpool(Kp, Sp)
__global__ void bn_relu_pool(const float* __restrict__ Y, const float* __restrict__ mean,
                             const float* __restrict__ var, const float* __restrict__ g,
                             const float* __restrict__ bta, float* __restrict__ O,
                             int C, int Lin, int Lout, int Kp, int Sp) {
    int o = blockIdx.x * 256 + threadIdx.x;
    if (o >= Bn * C * Lout) return;
    int j = o % Lout, c = (o / Lout) % C, b = o / (Lout * C);
    float sc = g[c] * rsqrtf(var[c] + 1e-5f);
    float sh = bta[c] - mean[c] * sc;
    const float* yrow = Y + ((size_t)b * C + c) * Lin + (size_t)j * Sp;
    float m = -1e30f;
    for (int k = 0; k < Kp; ++k) {
        float v = fmaxf(yrow[k] * sc + sh, 0.f);
        m = fmaxf(m, v);
    }
    O[((size_t)b * C + c) * Lout + j] = m;
}

__global__ void final_dot(const float* __restrict__ Y2, const float* __restrict__ Z2,
                          const float* __restrict__ wy, const float* __restrict__ by,
                          const float* __restrict__ wz, const float* __restrict__ bz,
                          float* __restrict__ prod) {
    const int b = blockIdx.y, j = blockIdx.x, t = threadIdx.x;  // 128 threads
    float p0 = 0, p1 = 0, q0 = 0, q1 = 0;
    for (int c = t; c < FOUT; c += 128) {
        float v = Y2[((size_t)b * FOUT + c) * 255 + j];
        p0 += v * wy[c]; p1 += v * wy[FOUT + c];
    }
    for (int c = t; c < CCAT; c += 128) {
        float v = Z2[((size_t)b * CCAT + c) * 255 + j];
        q0 += v * wz[c]; q1 += v * wz[CCAT + c];
    }
    __shared__ float r0[128], r1[128], r2[128], r3[128];
    r0[t] = p0; r1[t] = p1; r2[t] = q0; r3[t] = q1;
    __syncthreads();
    for (int s = 64; s; s >>= 1) {
        if (t < s) { r0[t] += r0[t + s]; r1[t] += r1[t + s]; r2[t] += r2[t + s]; r3[t] += r3[t + s]; }
        __syncthreads();
    }
    if (t == 0) {
        float y0 = r0[0] + by[0], y1 = r1[0] + by[1];
        float z0 = r2[0] + bz[0], z1 = r3[0] + bz[1];
        prod[((size_t)b * 255 + j) * 2 + 0] = y0 * z0;
        prod[((size_t)b * 255 + j) * 2 + 1] = y1 * z1;
    }
}

__global__ void final_out(const float* __restrict__ prod, float* __restrict__ out) {
    const int b = blockIdx.x, t = threadIdx.x;
    const int w = t >> 6, lane = t & 63;
    float s = 0.f;
    for (int j = lane; j < 255; j += 64) s += prod[((size_t)b * 255 + j) * 2 + w];
#pragma unroll
    for (int off = 32; off; off >>= 1) s += __shfl_down(s, off);
    if (lane == 0) out[b * 2 + w] = 1.f / (1.f + expf(-s / 255.f));
}

// ---------------- launch ----------------
extern "C" void kernel_launch(void* const* d_in, const int* in_sizes, int n_in,
                              void* d_out, int out_size, void* d_ws, size_t ws_size,
                              hipStream_t stream) {
    (void)in_sizes; (void)n_in; (void)out_size; (void)ws_size;
    const float* features = (const float*)d_in[0];
    const int*   src      = (const int*)d_in[1];
    const int*   dst      = (const int*)d_in[2];
    const int*   etype    = (const int*)d_in[3];
    const float* W_lin    = (const float*)d_in[4];
    const float* b_lin    = (const float*)d_in[5];   // [2][256] contiguous = 512-bias
    const float* W_ih     = (const float*)d_in[6];
    const float* W_hh     = (const float*)d_in[7];
    const float* b_ih     = (const float*)d_in[8];
    const float* b_hh     = (const float*)d_in[9];
    const float* conv1_w  = (const float*)d_in[10];
    const float* conv1_b  = (const float*)d_in[11];
    const float* conv2_w  = (const float*)d_in[12];
    const float* conv2_b  = (const float*)d_in[13];
    const float* convc1_w = (const float*)d_in[14];
    const float* convc1_b = (const float*)d_in[15];
    const float* convc2_w = (const float*)d_in[16];
    const float* convc2_b = (const float*)d_in[17];
    const float* bn_g     = (const float*)d_in[18];
    const float* bn_b     = (const float*)d_in[19];
    const float* bnc_g    = (const float*)d_in[20];
    const float* bnc_b    = (const float*)d_in[21];
    const float* mlpy_w   = (const float*)d_in[22];
    const float* mlpy_b   = (const float*)d_in[23];
    const float* mlpz_w   = (const float*)d_in[24];
    const float* mlpz_b   = (const float*)d_in[25];

    float* ws = (float*)d_ws;
    // float-offset layout
    float*          h    = ws;                                   // 4,194,304
    unsigned short* hb   = (unsigned short*)(ws + 4194304);      // 2,097,152 fslots
    unsigned short* aggb = (unsigned short*)(ws + 6291456);      // 2,097,152 fslots
    float*          bufA = ws + 8388608;                         // 12,582,912 (Whb / gi / conv-Y)
    float*          bufB = ws + 20971520;                        // 12,582,912 (gh / conv-Z)
    unsigned short* Wb   = (unsigned short*)(ws + 33554432);     // 262,144 fslots
    float*          sreg = ws + 33816576;                        // stats + prod
    int*            ib   = (int*)(ws + 33825536);                // CSR ints
    int* deg    = ib;
    int* cursor = ib + 16384;
    int* rowptr = ib + 32768;          // 16385
    int* widx   = ib + 49160;          // 262144

    unsigned short* Wlin_b = Wb;               // [512][256]
    unsigned short* Wih_b  = Wb + 131072;      // [768][256]
    unsigned short* Whh_b  = Wb + 327680;      // [768][256]
    unsigned short* Whb    = (unsigned short*)bufA;  // [16384][512] bf16

    // ---- weight conversion + CSR build (per launch, graph-safe) ----
    cvt_bf<<<512,  256, 0, stream>>>(W_lin, Wlin_b, 131072);
    cvt_bf<<<768,  256, 0, stream>>>(W_ih,  Wih_b,  196608);
    cvt_bf<<<768,  256, 0, stream>>>(W_hh,  Whh_b,  196608);
    pad_h<<<Nn * FOUT / 256, 256, 0, stream>>>(features, h, hb);

    hipMemsetAsync(deg, 0, 16384 * sizeof(int), stream);
    edge_count<<<NE / 256, 256, 0, stream>>>(dst, deg);
    scan_deg<<<1, 1024, 0, stream>>>(deg, rowptr, cursor);
    edge_fill<<<NE / 256, 256, 0, stream>>>(src, dst, etype, cursor, widx);

    // ---- GGNN steps ----
    for (int s6 = 0; s6 < STEPS; ++s6) {
        // Wh = h @ [Wlin0;Wlin1]^T + [b0;b1]  -> bf16 [16384][512]
        gemm_mfma<<<dim3(512 / 64, Nn / 128), 256, 0, stream>>>(
            hb, Wlin_b, b_lin, nullptr, Whb, 512, 1);
        gather_agg<<<Nn, 64, 0, stream>>>(Whb, rowptr, widx, aggb);
        gemm_mfma<<<dim3(768 / 64, Nn / 128), 256, 0, stream>>>(
            hb, Whh_b, b_hh, bufB, nullptr, 768, 0);
        gemm_mfma<<<dim3(768 / 64, Nn / 128), 256, 0, stream>>>(
            aggb, Wih_b, b_ih, bufA, nullptr, 768, 0);
        gru_update<<<Nn * FOUT / 256, 256, 0, stream>>>(bufA, bufB, h, hb);
    }

    // ---- conv phase scratch layout ----
    float* cT    = bufB;                 // [16][384][1024]
    float* hT    = bufB + 6291456;       // [16][256][1024] (dead before Zbuf written)
    float* Ybuf  = bufA;                 // [16][256][1022]
    float* Y1p   = bufA + 4186112;       // [16][256][510]
    float* Y2buf = bufA + 6275072;       // [16][256][510]
    float* Y2    = bufA + 8364032;       // [16][256][255]
    float* Zbuf  = bufB + 6291456;       // [16][384][1022] (over dead hT)
    float* Z1p   = bufB;                 // [16][384][510]  (over dead cT)
    float* Z2buf = bufB + 3133440;       // [16][384][510]
    float* Z2    = bufB + 6291456;       // [16][384][255]  (over dead Zbuf head)
    float* meanb = sreg;
    float* varb  = sreg + 384;
    float* prod  = sreg + 768;           // [16][255][2]

    transpose_hT<<<Bn * FOUT * NPG / 256, 256, 0, stream>>>(h, hT);
    build_cT<<<Bn * CCAT * NPG / 256, 256, 0, stream>>>(h, features, cT);

    // Y branch (must fully consume hT before Z conv k3 writes Zbuf)
    conv_tiled<3><<<dim3(16, FOUT / 64, Bn), 256, 0, stream>>>(hT, conv1_w, conv1_b, Ybuf, FOUT, 1024, 1022);
    bn_stats<<<FOUT, 256, 0, stream>>>(Ybuf, meanb, varb, FOUT, 1022);
    bn_relu_pool<<<(Bn * FOUT * 510 + 255) / 256, 256, 0, stream>>>(
        Ybuf, meanb, varb, bn_g, bn_b, Y1p, FOUT, 1022, 510, 3, 2);
    conv_tiled<1><<<dim3(8, FOUT / 64, Bn), 256, 0, stream>>>(Y1p, conv2_w, conv2_b, Y2buf, FOUT, 510, 510);
    bn_stats<<<FOUT, 256, 0, stream>>>(Y2buf, meanb, varb, FOUT, 510);
    bn_relu_pool<<<(Bn * FOUT * 255 + 255) / 256, 256, 0, stream>>>(
        Y2buf, meanb, varb, bn_g, bn_b, Y2, FOUT, 510, 255, 2, 2);

    // Z branch
    conv_tiled<3><<<dim3(16, CCAT / 64, Bn), 256, 0, stream>>>(cT, convc1_w, convc1_b, Zbuf, CCAT, 1024, 1022);
    bn_stats<<<CCAT, 256, 0, stream>>>(Zbuf, meanb, varb, CCAT, 1022);
    bn_relu_pool<<<(Bn * CCAT * 510 + 255) / 256, 256, 0, stream>>>(
        Zbuf, meanb, varb, bnc_g, bnc_b, Z1p, CCAT, 1022, 510, 3, 2);
    conv_tiled<1><<<dim3(8, CCAT / 64, Bn), 256, 0, stream>>>(Z1p, convc2_w, convc2_b, Z2buf, CCAT, 510, 510);
    bn_stats<<<CCAT, 256, 0, stream>>>(Z2buf, meanb, varb, CCAT, 510);
    bn_relu_pool<<<(Bn * CCAT * 255 + 255) / 256, 256, 0, stream>>>(
        Z2buf, meanb, varb, bnc_g, bnc_b, Z2, CCAT, 510, 255, 2, 2);

    final_dot<<<dim3(255, Bn), 128, 0, stream>>>(Y2, Z2, mlpy_w, mlpy_b, mlpz_w, mlpz_b, prod);
    final_out<<<Bn, 128, 0, stream>>>(prod, (float*)d_out);
}

// Round 4
// 1182.816 us; speedup vs baseline: 8.7167x; 1.0998x over previous
//
#include <hip/hip_runtime.h>
#include <math.h>

// ---------------- problem constants ----------------
constexpr int Bn     = 16;
constexpr int NPG    = 1024;
constexpr int Nn     = Bn * NPG;     // 16384 nodes
constexpr int FIN    = 128;
constexpr int FOUT   = 256;
constexpr int CCAT   = 384;
constexpr int STEPS  = 6;
constexpr int NE     = 262144;

using short8 = __attribute__((ext_vector_type(8))) short;
using f32x4  = __attribute__((ext_vector_type(4))) float;

static __device__ __forceinline__ unsigned short f2bf(float x) {
    union { float f; unsigned u; } v; v.f = x;
    unsigned r = (v.u + 0x7FFFu + ((v.u >> 16) & 1u)) >> 16;
    return (unsigned short)r;
}
static __device__ __forceinline__ float bf2f(unsigned short b) {
    union { unsigned u; float f; } v; v.u = ((unsigned)b) << 16;
    return v.f;
}

// ---------------- small utility kernels ----------------

__global__ void cvt_bf(const float* __restrict__ s, unsigned short* __restrict__ d, int n) {
    int i = blockIdx.x * 256 + threadIdx.x;
    if (i < n) d[i] = f2bf(s[i]);
}

// conv weight reorder+convert: Wt[c][kb*C+i] = W[c][i][kb]  (square convs: C_out==C_in==C)
__global__ void cvt_wconv(const float* __restrict__ W, unsigned short* __restrict__ Wt,
                          int C, int KW, int n) {
    int o = blockIdx.x * 256 + threadIdx.x;
    if (o >= n) return;
    int c = o / (KW * C), rem = o % (KW * C);
    int kb = rem / C, i = rem % C;
    Wt[o] = f2bf(W[(size_t)(c * C + i) * KW + kb]);
}

// h[n][k] = k<128 ? features[n][k] : 0 ; also bf16 copy
__global__ void pad_h(const float* __restrict__ f, float* __restrict__ h,
                      unsigned short* __restrict__ hb) {
    int i = blockIdx.x * 256 + threadIdx.x;
    int k = i & 255, n = i >> 8;
    float v = (k < FIN) ? f[(size_t)n * FIN + k] : 0.f;
    h[i] = v; hb[i] = f2bf(v);
}

// cb[n][c] = c<256 ? hb[n][c] : bf16(features[n][c-256])   (channel-last concat)
__global__ void build_cb(const unsigned short* __restrict__ hb, const float* __restrict__ f,
                         unsigned short* __restrict__ cb) {
    int idx = blockIdx.x * 256 + threadIdx.x;
    int c = idx % CCAT, n = idx / CCAT;
    cb[idx] = (c < FOUT) ? hb[(size_t)n * FOUT + c] : f2bf(f[(size_t)n * FIN + (c - FOUT)]);
}

// ---------------- CSR build (once per launch) ----------------

__global__ void edge_count(const int* __restrict__ dst, int* __restrict__ deg) {
    int e = blockIdx.x * 256 + threadIdx.x;
    atomicAdd(&deg[dst[e]], 1);
}

__global__ __launch_bounds__(1024) void scan_deg(const int* __restrict__ deg,
                                                 int* __restrict__ rowptr,
                                                 int* __restrict__ cursor) {
    __shared__ int ps[1024];
    const int t = threadIdx.x;
    int loc[16]; int s = 0;
    const int base = t * 16;
#pragma unroll
    for (int i = 0; i < 16; ++i) { loc[i] = deg[base + i]; s += loc[i]; }
    ps[t] = s;
    __syncthreads();
    for (int off = 1; off < 1024; off <<= 1) {
        int add = (t >= off) ? ps[t - off] : 0;
        __syncthreads();
        ps[t] += add;
        __syncthreads();
    }
    int run = ps[t] - s;  // exclusive prefix
#pragma unroll
    for (int i = 0; i < 16; ++i) { rowptr[base + i] = run; cursor[base + i] = run; run += loc[i]; }
    if (t == 1023) rowptr[16384] = run;
}

__global__ void edge_fill(const int* __restrict__ src, const int* __restrict__ dst,
                          const int* __restrict__ et, int* __restrict__ cursor,
                          int* __restrict__ widx) {
    int e = blockIdx.x * 256 + threadIdx.x;
    int slot = atomicAdd(&cursor[dst[e]], 1);
    widx[slot] = src[e] * 2 + et[e];   // row index into Wh[16384][512] grouped by 256
}

// ---------------- bf16 MFMA GEMM (GGNN) ----------------
// C[M,N] = A[M,256] @ W[N,256]^T + bias. Tile 128(M) x 64(N), 4 waves.
__global__ __launch_bounds__(256) void gemm_mfma(
    const unsigned short* __restrict__ A, const unsigned short* __restrict__ W,
    const float* __restrict__ bias, float* __restrict__ Cf,
    unsigned short* __restrict__ Cb, int N, int outBf) {
    constexpr int K = 256;
    __shared__ unsigned short As[128][72];
    __shared__ unsigned short Bs[64][72];
    const int t = threadIdx.x;
    const int w = t >> 6, l = t & 63;
    const int lr = l & 15, lk = (l >> 4) * 8;
    const int row0 = blockIdx.y * 128, col0 = blockIdx.x * 64;
    const int sr = t >> 3, sc = (t & 7) * 8;
    f32x4 acc[2][4] = {};

    for (int k0 = 0; k0 < K; k0 += 64) {
        __syncthreads();
#pragma unroll
        for (int p = 0; p < 4; ++p) {
            int r = p * 32 + sr;
            *(uint4*)&As[r][sc] = *(const uint4*)(A + (size_t)(row0 + r) * K + k0 + sc);
        }
#pragma unroll
        for (int p = 0; p < 2; ++p) {
            int r = p * 32 + sr;
            *(uint4*)&Bs[r][sc] = *(const uint4*)(W + (size_t)(col0 + r) * K + k0 + sc);
        }
        __syncthreads();
#pragma unroll
        for (int kk = 0; kk < 2; ++kk) {
            short8 a0 = *(const short8*)&As[w * 32 + lr][kk * 32 + lk];
            short8 a1 = *(const short8*)&As[w * 32 + 16 + lr][kk * 32 + lk];
            short8 b0 = *(const short8*)&Bs[lr][kk * 32 + lk];
            short8 b1 = *(const short8*)&Bs[16 + lr][kk * 32 + lk];
            short8 b2 = *(const short8*)&Bs[32 + lr][kk * 32 + lk];
            short8 b3 = *(const short8*)&Bs[48 + lr][kk * 32 + lk];
            acc[0][0] = __builtin_amdgcn_mfma_f32_16x16x32_bf16(a0, b0, acc[0][0], 0, 0, 0);
            acc[0][1] = __builtin_amdgcn_mfma_f32_16x16x32_bf16(a0, b1, acc[0][1], 0, 0, 0);
            acc[0][2] = __builtin_amdgcn_mfma_f32_16x16x32_bf16(a0, b2, acc[0][2], 0, 0, 0);
            acc[0][3] = __builtin_amdgcn_mfma_f32_16x16x32_bf16(a0, b3, acc[0][3], 0, 0, 0);
            acc[1][0] = __builtin_amdgcn_mfma_f32_16x16x32_bf16(a1, b0, acc[1][0], 0, 0, 0);
            acc[1][1] = __builtin_amdgcn_mfma_f32_16x16x32_bf16(a1, b1, acc[1][1], 0, 0, 0);
            acc[1][2] = __builtin_amdgcn_mfma_f32_16x16x32_bf16(a1, b2, acc[1][2], 0, 0, 0);
            acc[1][3] = __builtin_amdgcn_mfma_f32_16x16x32_bf16(a1, b3, acc[1][3], 0, 0, 0);
        }
    }
    const int rb = (l >> 4) * 4;
#pragma unroll
    for (int i = 0; i < 2; ++i)
#pragma unroll
        for (int j = 0; j < 4; ++j) {
            const int gcol = col0 + j * 16 + lr;
            const float bv = bias[gcol];
#pragma unroll
            for (int r = 0; r < 4; ++r) {
                const int grow = row0 + w * 32 + i * 16 + rb + r;
                float v = acc[i][j][r] + bv;
                if (outBf) Cb[(size_t)grow * N + gcol] = f2bf(v);
                else       Cf[(size_t)grow * N + gcol] = v;
            }
        }
}

// ---------------- bf16 MFMA implicit-GEMM conv1d (channel-last) ----------------
// X: [B][L][C] bf16, Wt: [N][KW*C] bf16 (k-major), Y: [B][Lv][N] fp32, Lv = L-KW+1.
// Tile: 128 spatial rows x 64 out-channels.
template<int KW>
__global__ __launch_bounds__(256) void conv_mfma(
    const unsigned short* __restrict__ X, const unsigned short* __restrict__ Wt,
    const float* __restrict__ bias, float* __restrict__ Y,
    int C, int L, int Lv, int N) {
    __shared__ unsigned short As[128][72];
    __shared__ unsigned short Bs[64][72];
    const int t = threadIdx.x;
    const int w = t >> 6, l = t & 63;
    const int lr = l & 15, lk = (l >> 4) * 8;
    const int b = blockIdx.z;
    const int l0 = blockIdx.y * 128, col0 = blockIdx.x * 64;
    const int sr = t >> 3, sc = (t & 7) * 8;
    const unsigned short* Xb = X + (size_t)b * L * C;
    const int KWC = KW * C;
    f32x4 acc[2][4] = {};

    for (int kb = 0; kb < KW; ++kb) {
        for (int i0 = 0; i0 < C; i0 += 64) {
            __syncthreads();
#pragma unroll
            for (int p = 0; p < 4; ++p) {
                int r = p * 32 + sr;
                int row = l0 + r + kb; row = row < L ? row : L - 1;   // clamp (discarded rows)
                *(uint4*)&As[r][sc] = *(const uint4*)(Xb + (size_t)row * C + i0 + sc);
            }
#pragma unroll
            for (int p = 0; p < 2; ++p) {
                int r = p * 32 + sr;
                *(uint4*)&Bs[r][sc] = *(const uint4*)(Wt + (size_t)(col0 + r) * KWC + kb * C + i0 + sc);
            }
            __syncthreads();
#pragma unroll
            for (int kk = 0; kk < 2; ++kk) {
                short8 a0 = *(const short8*)&As[w * 32 + lr][kk * 32 + lk];
                short8 a1 = *(const short8*)&As[w * 32 + 16 + lr][kk * 32 + lk];
                short8 b0 = *(const short8*)&Bs[lr][kk * 32 + lk];
                short8 b1 = *(const short8*)&Bs[16 + lr][kk * 32 + lk];
                short8 b2 = *(const short8*)&Bs[32 + lr][kk * 32 + lk];
                short8 b3 = *(const short8*)&Bs[48 + lr][kk * 32 + lk];
                acc[0][0] = __builtin_amdgcn_mfma_f32_16x16x32_bf16(a0, b0, acc[0][0], 0, 0, 0);
                acc[0][1] = __builtin_amdgcn_mfma_f32_16x16x32_bf16(a0, b1, acc[0][1], 0, 0, 0);
                acc[0][2] = __builtin_amdgcn_mfma_f32_16x16x32_bf16(a0, b2, acc[0][2], 0, 0, 0);
                acc[0][3] = __builtin_amdgcn_mfma_f32_16x16x32_bf16(a0, b3, acc[0][3], 0, 0, 0);
                acc[1][0] = __builtin_amdgcn_mfma_f32_16x16x32_bf16(a1, b0, acc[1][0], 0, 0, 0);
                acc[1][1] = __builtin_amdgcn_mfma_f32_16x16x32_bf16(a1, b1, acc[1][1], 0, 0, 0);
                acc[1][2] = __builtin_amdgcn_mfma_f32_16x16x32_bf16(a1, b2, acc[1][2], 0, 0, 0);
                acc[1][3] = __builtin_amdgcn_mfma_f32_16x16x32_bf16(a1, b3, acc[1][3], 0, 0, 0);
            }
        }
    }
    const int rb = (l >> 4) * 4;
#pragma unroll
    for (int i = 0; i < 2; ++i)
#pragma unroll
        for (int j = 0; j < 4; ++j) {
            const int gcol = col0 + j * 16 + lr;
            const float bv = bias[gcol];
#pragma unroll
            for (int r = 0; r < 4; ++r) {
                const int grow = l0 + w * 32 + i * 16 + rb + r;
                if (grow < Lv)
                    Y[((size_t)b * Lv + grow) * N + gcol] = acc[i][j][r] + bv;
            }
        }
}

// ---------------- CSR gather aggregation ----------------
__global__ __launch_bounds__(64) void gather_agg(
    const unsigned short* __restrict__ Whb, const int* __restrict__ rowptr,
    const int* __restrict__ widx, unsigned short* __restrict__ aggb) {
    const int n = blockIdx.x, t = threadIdx.x;  // 64 threads, 4 ch each
    float a0 = 0, a1 = 0, a2 = 0, a3 = 0;
    const int s0 = rowptr[n], s1 = rowptr[n + 1];
    for (int s = s0; s < s1; ++s) {
        const ushort4 v = *(const ushort4*)(Whb + (size_t)widx[s] * 256 + t * 4);
        a0 += bf2f(v.x); a1 += bf2f(v.y); a2 += bf2f(v.z); a3 += bf2f(v.w);
    }
    ushort4 o; o.x = f2bf(a0); o.y = f2bf(a1); o.z = f2bf(a2); o.w = f2bf(a3);
    *(ushort4*)(aggb + (size_t)n * 256 + t * 4) = o;
}

// GRU cell update, in-place h (+ bf16 copy)
__global__ void gru_update(const float* __restrict__ gi, const float* __restrict__ gh,
                           float* __restrict__ h, unsigned short* __restrict__ hb) {
    int i = blockIdx.x * 256 + threadIdx.x;
    int n = i >> 8, k = i & 255;
    size_t base = (size_t)n * 768;
    float ir = gi[base + k], iz = gi[base + 256 + k], ig = gi[base + 512 + k];
    float hr = gh[base + k], hz = gh[base + 256 + k], hg = gh[base + 512 + k];
    float r  = 1.f / (1.f + expf(-(ir + hr)));
    float z  = 1.f / (1.f + expf(-(iz + hz)));
    float nn = tanhf(ig + r * hg);
    float hv = (1.f - z) * nn + z * h[i];
    h[i] = hv; hb[i] = f2bf(hv);
}

// ---------------- BN stats (channel-last, two-pass, deterministic) ----------------
__global__ void bn_part_cl(const float* __restrict__ X, float* __restrict__ pS,
                           float* __restrict__ pQ, int C, int totalRows, int chunk) {
    const int blk = blockIdx.x, c = threadIdx.x;
    const int r0 = blk * chunk;
    const int r1 = min(r0 + chunk, totalRows);
    float s = 0.f, q = 0.f;
    for (int r = r0; r < r1; ++r) {
        float v = X[(size_t)r * C + c];
        s += v; q += v * v;
    }
    pS[(size_t)blk * C + c] = s;
    pQ[(size_t)blk * C + c] = q;
}

__global__ void bn_reduce_cl(const float* __restrict__ pS, const float* __restrict__ pQ,
                             float* __restrict__ mean, float* __restrict__ var,
                             int C, int nblk, int totalRows) {
    const int c = threadIdx.x;
    float s = 0.f, q = 0.f;
    for (int b = 0; b < nblk; ++b) { s += pS[(size_t)b * C + c]; q += pQ[(size_t)b * C + c]; }
    float m = s / totalRows;
    mean[c] = m;
    var[c]  = q / totalRows - m * m;
}

// ---------------- fused BN + ReLU + maxpool (channel-last) ----------------
// out[b][j][c] = max_{k<Kp} relu(bn(X[b][j*2+k][c]))
__global__ void bnp_cl(const float* __restrict__ X, const float* __restrict__ mean,
                       const float* __restrict__ var, const float* __restrict__ g,
                       const float* __restrict__ bta, float* __restrict__ Of,
                       unsigned short* __restrict__ Ob, int C, int Lin, int Lout,
                       int Kp, int outBf) {
    int idx = blockIdx.x * 256 + threadIdx.x;
    if (idx >= Bn * Lout * C) return;
    int c = idx % C, j = (idx / C) % Lout, b = idx / (C * Lout);
    float sc = g[c] * rsqrtf(var[c] + 1e-5f);
    float sh = bta[c] - mean[c] * sc;
    const float* xb = X + ((size_t)b * Lin + j * 2) * C + c;
    float m = 0.f;                                    // relu floor
    for (int k = 0; k < Kp; ++k) m = fmaxf(m, xb[(size_t)k * C] * sc + sh);
    if (outBf) Ob[idx] = f2bf(m);
    else       Of[idx] = m;
}

// ---------------- final gating ----------------
__global__ void final_dot(const float* __restrict__ Y2, const float* __restrict__ Z2,
                          const float* __restrict__ wy, const float* __restrict__ by,
                          const float* __restrict__ wz, const float* __restrict__ bz,
                          float* __restrict__ prod) {
    const int b = blockIdx.y, j = blockIdx.x, t = threadIdx.x;  // 128 threads
    float p0 = 0, p1 = 0, q0 = 0, q1 = 0;
    const float* yrow = Y2 + (size_t)(b * 255 + j) * FOUT;
    const float* zrow = Z2 + (size_t)(b * 255 + j) * CCAT;
    for (int c = t; c < FOUT; c += 128) {
        float v = yrow[c];
        p0 += v * wy[c]; p1 += v * wy[FOUT + c];
    }
    for (int c = t; c < CCAT; c += 128) {
        float v = zrow[c];
        q0 += v * wz[c]; q1 += v * wz[CCAT + c];
    }
    __shared__ float r0[128], r1[128], r2[128], r3[128];
    r0[t] = p0; r1[t] = p1; r2[t] = q0; r3[t] = q1;
    __syncthreads();
    for (int s = 64; s; s >>= 1) {
        if (t < s) { r0[t] += r0[t + s]; r1[t] += r1[t + s]; r2[t] += r2[t + s]; r3[t] += r3[t + s]; }
        __syncthreads();
    }
    if (t == 0) {
        float y0 = r0[0] + by[0], y1 = r1[0] + by[1];
        float z0 = r2[0] + bz[0], z1 = r3[0] + bz[1];
        prod[((size_t)b * 255 + j) * 2 + 0] = y0 * z0;
        prod[((size_t)b * 255 + j) * 2 + 1] = y1 * z1;
    }
}

__global__ void final_out(const float* __restrict__ prod, float* __restrict__ out) {
    const int b = blockIdx.x, t = threadIdx.x;
    const int w = t >> 6, lane = t & 63;
    float s = 0.f;
    for (int j = lane; j < 255; j += 64) s += prod[((size_t)b * 255 + j) * 2 + w];
#pragma unroll
    for (int off = 32; off; off >>= 1) s += __shfl_down(s, off);
    if (lane == 0) out[b * 2 + w] = 1.f / (1.f + expf(-s / 255.f));
}

// ---------------- launch ----------------
extern "C" void kernel_launch(void* const* d_in, const int* in_sizes, int n_in,
                              void* d_out, int out_size, void* d_ws, size_t ws_size,
                              hipStream_t stream) {
    (void)in_sizes; (void)n_in; (void)out_size; (void)ws_size;
    const float* features = (const float*)d_in[0];
    const int*   src      = (const int*)d_in[1];
    const int*   dst      = (const int*)d_in[2];
    const int*   etype    = (const int*)d_in[3];
    const float* W_lin    = (const float*)d_in[4];
    const float* b_lin    = (const float*)d_in[5];   // [2][256] contiguous = 512-bias
    const float* W_ih     = (const float*)d_in[6];
    const float* W_hh     = (const float*)d_in[7];
    const float* b_ih     = (const float*)d_in[8];
    const float* b_hh     = (const float*)d_in[9];
    const float* conv1_w  = (const float*)d_in[10];
    const float* conv1_b  = (const float*)d_in[11];
    const float* conv2_w  = (const float*)d_in[12];
    const float* conv2_b  = (const float*)d_in[13];
    const float* convc1_w = (const float*)d_in[14];
    const float* convc1_b = (const float*)d_in[15];
    const float* convc2_w = (const float*)d_in[16];
    const float* convc2_b = (const float*)d_in[17];
    const float* bn_g     = (const float*)d_in[18];
    const float* bn_b     = (const float*)d_in[19];
    const float* bnc_g    = (const float*)d_in[20];
    const float* bnc_b    = (const float*)d_in[21];
    const float* mlpy_w   = (const float*)d_in[22];
    const float* mlpy_b   = (const float*)d_in[23];
    const float* mlpz_w   = (const float*)d_in[24];
    const float* mlpz_b   = (const float*)d_in[25];

    float* ws = (float*)d_ws;
    // ---- GGNN-phase layout (float offsets) ----
    float*          h    = ws;                                   // 4,194,304 f
    unsigned short* hb   = (unsigned short*)(ws + 4194304);      // 2,097,152 f-slots
    unsigned short* aggb = (unsigned short*)(ws + 6291456);      // 2,097,152 f-slots
    float*          bufA = ws + 8388608;                         // 12,582,912 f (Whb / gi / conv-Y)
    float*          bufB = ws + 20971520;                        // 12,582,912 f (gh / conv-Z)
    unsigned short* Wb   = (unsigned short*)(ws + 33554432);     // 262,144 f-slots
    int*            ib   = (int*)(ws + 33825536);                // CSR ints
    int* deg    = ib;
    int* cursor = ib + 16384;
    int* rowptr = ib + 32768;          // 16385
    int* widx   = ib + 49160;          // 262144

    unsigned short* Wlin_b = Wb;               // [512][256]
    unsigned short* Wih_b  = Wb + 131072;      // [768][256]
    unsigned short* Whh_b  = Wb + 327680;      // [768][256]
    unsigned short* Whb    = (unsigned short*)bufA;  // [16384][512] bf16

    // ---- weight conversion + CSR build ----
    cvt_bf<<<512,  256, 0, stream>>>(W_lin, Wlin_b, 131072);
    cvt_bf<<<768,  256, 0, stream>>>(W_ih,  Wih_b,  196608);
    cvt_bf<<<768,  256, 0, stream>>>(W_hh,  Whh_b,  196608);
    pad_h<<<Nn * FOUT / 256, 256, 0, stream>>>(features, h, hb);

    hipMemsetAsync(deg, 0, 16384 * sizeof(int), stream);
    edge_count<<<NE / 256, 256, 0, stream>>>(dst, deg);
    scan_deg<<<1, 1024, 0, stream>>>(deg, rowptr, cursor);
    edge_fill<<<NE / 256, 256, 0, stream>>>(src, dst, etype, cursor, widx);

    // ---- GGNN steps ----
    for (int s6 = 0; s6 < STEPS; ++s6) {
        gemm_mfma<<<dim3(512 / 64, Nn / 128), 256, 0, stream>>>(
            hb, Wlin_b, b_lin, nullptr, Whb, 512, 1);
        gather_agg<<<Nn, 64, 0, stream>>>(Whb, rowptr, widx, aggb);
        gemm_mfma<<<dim3(768 / 64, Nn / 128), 256, 0, stream>>>(
            hb, Whh_b, b_hh, bufB, nullptr, 768, 0);
        gemm_mfma<<<dim3(768 / 64, Nn / 128), 256, 0, stream>>>(
            aggb, Wih_b, b_ih, bufA, nullptr, 768, 0);
        gru_update<<<Nn * FOUT / 256, 256, 0, stream>>>(bufA, bufB, h, hb);
    }

    // ---- conv-phase layout (channel-last) ----
    unsigned short* cb    = (unsigned short*)ws;                 // [16384][384] bf16 (over dead h)
    float*          Yc1   = bufA;                                // [16352][256] f32
    unsigned short* P1y   = (unsigned short*)(bufA + 4186112);   // [8160][256] bf16
    float*          Yc2   = bufA + 5230592;                      // [8160][256] f32
    float*          Y2    = bufA + 7319552;                      // [4080][256] f32
    float*          Z2    = bufA + 8364032;                      // [4080][384] f32
    float*          Zc1   = bufB;                                // [16352][384] f32
    unsigned short* P1z   = (unsigned short*)(bufB + 6279168);   // [8160][384] bf16
    float*          Zc2   = bufB + 7845888;                      // [8160][384] f32 (ends 10,979,328)
    unsigned short* Wcv   = (unsigned short*)(bufB + 11000000);  // conv weights bf16 (gh dead)
    unsigned short* c1b   = Wcv;                                 // [256][768]
    unsigned short* c2b   = Wcv + 196608;                        // [256][256]
    unsigned short* cc1b  = Wcv + 262144;                        // [384][1152]
    unsigned short* cc2b  = Wcv + 704512;                        // [384][384]
    float* sreg  = (float*)aggb;                                 // stats region (aggb dead)
    float* meanb = sreg;            // 384
    float* varb  = sreg + 384;      // 384
    float* pS    = sreg + 1024;     // 64*384
    float* pQ    = sreg + 25600;    // 64*384
    float* prod  = sreg + 50176;    // [16][255][2]

    // conv weights (convert after GGNN: bufB/gh is dead now)
    cvt_wconv<<<768,  256, 0, stream>>>(conv1_w,  c1b,  FOUT, 3, FOUT * FOUT * 3);
    cvt_wconv<<<256,  256, 0, stream>>>(conv2_w,  c2b,  FOUT, 1, FOUT * FOUT);
    cvt_wconv<<<1728, 256, 0, stream>>>(convc1_w, cc1b, CCAT, 3, CCAT * CCAT * 3);
    cvt_wconv<<<576,  256, 0, stream>>>(convc2_w, cc2b, CCAT, 1, CCAT * CCAT);
    build_cb<<<Nn * CCAT / 256, 256, 0, stream>>>(hb, features, cb);

    // ---- Y branch ----
    conv_mfma<3><<<dim3(4, 8, Bn), 256, 0, stream>>>(hb, c1b, conv1_b, Yc1, FOUT, 1024, 1022, FOUT);
    bn_part_cl<<<64, FOUT, 0, stream>>>(Yc1, pS, pQ, FOUT, Bn * 1022, 256);
    bn_reduce_cl<<<1, FOUT, 0, stream>>>(pS, pQ, meanb, varb, FOUT, 64, Bn * 1022);
    bnp_cl<<<(Bn * 510 * FOUT + 255) / 256, 256, 0, stream>>>(
        Yc1, meanb, varb, bn_g, bn_b, nullptr, P1y, FOUT, 1022, 510, 3, 1);
    conv_mfma<1><<<dim3(4, 4, Bn), 256, 0, stream>>>(P1y, c2b, conv2_b, Yc2, FOUT, 510, 510, FOUT);
    bn_part_cl<<<64, FOUT, 0, stream>>>(Yc2, pS, pQ, FOUT, Bn * 510, 128);
    bn_reduce_cl<<<1, FOUT, 0, stream>>>(pS, pQ, meanb, varb, FOUT, 64, Bn * 510);
    bnp_cl<<<(Bn * 255 * FOUT + 255) / 256, 256, 0, stream>>>(
        Yc2, meanb, varb, bn_g, bn_b, Y2, nullptr, FOUT, 510, 255, 2, 0);

    // ---- Z branch ----
    conv_mfma<3><<<dim3(6, 8, Bn), 256, 0, stream>>>(cb, cc1b, convc1_b, Zc1, CCAT, 1024, 1022, CCAT);
    bn_part_cl<<<64, CCAT, 0, stream>>>(Zc1, pS, pQ, CCAT, Bn * 1022, 256);
    bn_reduce_cl<<<1, CCAT, 0, stream>>>(pS, pQ, meanb, varb, CCAT, 64, Bn * 1022);
    bnp_cl<<<(Bn * 510 * CCAT + 255) / 256, 256, 0, stream>>>(
        Zc1, meanb, varb, bnc_g, bnc_b, nullptr, P1z, CCAT, 1022, 510, 3, 1);
    conv_mfma<1><<<dim3(6, 4, Bn), 256, 0, stream>>>(P1z, cc2b, convc2_b, Zc2, CCAT, 510, 510, CCAT);
    bn_part_cl<<<64, CCAT, 0, stream>>>(Zc2, pS, pQ, CCAT, Bn * 510, 128);
    bn_reduce_cl<<<1, CCAT, 0, stream>>>(pS, pQ, meanb, varb, CCAT, 64, Bn * 510);
    bnp_cl<<<(Bn * 255 * CCAT + 255) / 256, 256, 0, stream>>>(
        Zc2, meanb, varb, bnc_g, bnc_b, Z2, nullptr, CCAT, 510, 255, 2, 0);

    // ---- gating + mean + sigmoid ----
    final_dot<<<dim3(255, Bn), 128, 0, stream>>>(Y2, Z2, mlpy_w, mlpy_b, mlpz_w, mlpz_b, prod);
    final_out<<<Bn, 128, 0, stream>>>(prod, (float*)d_out);
}

// Round 5
// 953.719 us; speedup vs baseline: 10.8105x; 1.2402x over previous
//
#include <hip/hip_runtime.h>
#include <math.h>

// ---------------- problem constants ----------------
constexpr int Bn     = 16;
constexpr int NPG    = 1024;
constexpr int Nn     = Bn * NPG;     // 16384 nodes
constexpr int FIN    = 128;
constexpr int FOUT   = 256;
constexpr int CCAT   = 384;
constexpr int STEPS  = 6;
constexpr int NE     = 262144;

using short8 = __attribute__((ext_vector_type(8))) short;
using f32x4  = __attribute__((ext_vector_type(4))) float;

static __device__ __forceinline__ unsigned short f2bf(float x) {
    union { float f; unsigned u; } v; v.f = x;
    unsigned r = (v.u + 0x7FFFu + ((v.u >> 16) & 1u)) >> 16;
    return (unsigned short)r;
}
static __device__ __forceinline__ float bf2f(unsigned short b) {
    union { unsigned u; float f; } v; v.u = ((unsigned)b) << 16;
    return v.f;
}

// ---------------- small utility kernels ----------------

__global__ void cvt_bf(const float* __restrict__ s, unsigned short* __restrict__ d, int n) {
    int i = blockIdx.x * 256 + threadIdx.x;
    if (i < n) d[i] = f2bf(s[i]);
}

// conv weight reorder+convert: Wt[c][kb*C+i] = W[c][i][kb]
__global__ void cvt_wconv(const float* __restrict__ W, unsigned short* __restrict__ Wt,
                          int C, int KW, int n) {
    int o = blockIdx.x * 256 + threadIdx.x;
    if (o >= n) return;
    int c = o / (KW * C), rem = o % (KW * C);
    int kb = rem / C, i = rem % C;
    Wt[o] = f2bf(W[(size_t)(c * C + i) * KW + kb]);
}

// h[n][k] = k<128 ? features[n][k] : 0 ; also bf16 copy
__global__ void pad_h(const float* __restrict__ f, float* __restrict__ h,
                      unsigned short* __restrict__ hb) {
    int i = blockIdx.x * 256 + threadIdx.x;
    int k = i & 255, n = i >> 8;
    float v = (k < FIN) ? f[(size_t)n * FIN + k] : 0.f;
    h[i] = v; hb[i] = f2bf(v);
}

// cb[n][c] = c<256 ? hb[n][c] : bf16(features[n][c-256])
__global__ void build_cb(const unsigned short* __restrict__ hb, const float* __restrict__ f,
                         unsigned short* __restrict__ cb) {
    int idx = blockIdx.x * 256 + threadIdx.x;
    int c = idx % CCAT, n = idx / CCAT;
    cb[idx] = (c < FOUT) ? hb[(size_t)n * FOUT + c] : f2bf(f[(size_t)n * FIN + (c - FOUT)]);
}

// ---------------- CSR build (once per launch) ----------------

__global__ void edge_count(const int* __restrict__ dst, int* __restrict__ deg) {
    int e = blockIdx.x * 256 + threadIdx.x;
    atomicAdd(&deg[dst[e]], 1);
}

__global__ __launch_bounds__(1024) void scan_deg(const int* __restrict__ deg,
                                                 int* __restrict__ rowptr,
                                                 int* __restrict__ cursor) {
    __shared__ int ps[1024];
    const int t = threadIdx.x;
    int loc[16]; int s = 0;
    const int base = t * 16;
#pragma unroll
    for (int i = 0; i < 16; ++i) { loc[i] = deg[base + i]; s += loc[i]; }
    ps[t] = s;
    __syncthreads();
    for (int off = 1; off < 1024; off <<= 1) {
        int add = (t >= off) ? ps[t - off] : 0;
        __syncthreads();
        ps[t] += add;
        __syncthreads();
    }
    int run = ps[t] - s;
#pragma unroll
    for (int i = 0; i < 16; ++i) { rowptr[base + i] = run; cursor[base + i] = run; run += loc[i]; }
    if (t == 1023) rowptr[16384] = run;
}

__global__ void edge_fill(const int* __restrict__ src, const int* __restrict__ dst,
                          const int* __restrict__ et, int* __restrict__ cursor,
                          int* __restrict__ widx) {
    int e = blockIdx.x * 256 + threadIdx.x;
    int slot = atomicAdd(&cursor[dst[e]], 1);
    widx[slot] = src[e] * 2 + et[e];
}

// ---------------- bf16 MFMA GEMM (GGNN) ----------------
__global__ __launch_bounds__(256) void gemm_mfma(
    const unsigned short* __restrict__ A, const unsigned short* __restrict__ W,
    const float* __restrict__ bias, float* __restrict__ Cf,
    unsigned short* __restrict__ Cb, int N, int outBf) {
    constexpr int K = 256;
    __shared__ unsigned short As[128][72];
    __shared__ unsigned short Bs[64][72];
    const int t = threadIdx.x;
    const int w = t >> 6, l = t & 63;
    const int lr = l & 15, lk = (l >> 4) * 8;
    const int row0 = blockIdx.y * 128, col0 = blockIdx.x * 64;
    const int sr = t >> 3, sc = (t & 7) * 8;
    f32x4 acc[2][4] = {};

    for (int k0 = 0; k0 < K; k0 += 64) {
        __syncthreads();
#pragma unroll
        for (int p = 0; p < 4; ++p) {
            int r = p * 32 + sr;
            *(uint4*)&As[r][sc] = *(const uint4*)(A + (size_t)(row0 + r) * K + k0 + sc);
        }
#pragma unroll
        for (int p = 0; p < 2; ++p) {
            int r = p * 32 + sr;
            *(uint4*)&Bs[r][sc] = *(const uint4*)(W + (size_t)(col0 + r) * K + k0 + sc);
        }
        __syncthreads();
#pragma unroll
        for (int kk = 0; kk < 2; ++kk) {
            short8 a0 = *(const short8*)&As[w * 32 + lr][kk * 32 + lk];
            short8 a1 = *(const short8*)&As[w * 32 + 16 + lr][kk * 32 + lk];
            short8 b0 = *(const short8*)&Bs[lr][kk * 32 + lk];
            short8 b1 = *(const short8*)&Bs[16 + lr][kk * 32 + lk];
            short8 b2 = *(const short8*)&Bs[32 + lr][kk * 32 + lk];
            short8 b3 = *(const short8*)&Bs[48 + lr][kk * 32 + lk];
            acc[0][0] = __builtin_amdgcn_mfma_f32_16x16x32_bf16(a0, b0, acc[0][0], 0, 0, 0);
            acc[0][1] = __builtin_amdgcn_mfma_f32_16x16x32_bf16(a0, b1, acc[0][1], 0, 0, 0);
            acc[0][2] = __builtin_amdgcn_mfma_f32_16x16x32_bf16(a0, b2, acc[0][2], 0, 0, 0);
            acc[0][3] = __builtin_amdgcn_mfma_f32_16x16x32_bf16(a0, b3, acc[0][3], 0, 0, 0);
            acc[1][0] = __builtin_amdgcn_mfma_f32_16x16x32_bf16(a1, b0, acc[1][0], 0, 0, 0);
            acc[1][1] = __builtin_amdgcn_mfma_f32_16x16x32_bf16(a1, b1, acc[1][1], 0, 0, 0);
            acc[1][2] = __builtin_amdgcn_mfma_f32_16x16x32_bf16(a1, b2, acc[1][2], 0, 0, 0);
            acc[1][3] = __builtin_amdgcn_mfma_f32_16x16x32_bf16(a1, b3, acc[1][3], 0, 0, 0);
        }
    }
    const int rb = (l >> 4) * 4;
#pragma unroll
    for (int i = 0; i < 2; ++i)
#pragma unroll
        for (int j = 0; j < 4; ++j) {
            const int gcol = col0 + j * 16 + lr;
            const float bv = bias[gcol];
#pragma unroll
            for (int r = 0; r < 4; ++r) {
                const int grow = row0 + w * 32 + i * 16 + rb + r;
                float v = acc[i][j][r] + bv;
                if (outBf) Cb[(size_t)grow * N + gcol] = f2bf(v);
                else       Cf[(size_t)grow * N + gcol] = v;
            }
        }
}

// ---------------- bf16 MFMA implicit-GEMM conv1d (channel-last) ----------------
template<int KW>
__global__ __launch_bounds__(256) void conv_mfma(
    const unsigned short* __restrict__ X, const unsigned short* __restrict__ Wt,
    const float* __restrict__ bias, float* __restrict__ Y,
    int C, int L, int Lv, int N) {
    __shared__ unsigned short As[128][72];
    __shared__ unsigned short Bs[64][72];
    const int t = threadIdx.x;
    const int w = t >> 6, l = t & 63;
    const int lr = l & 15, lk = (l >> 4) * 8;
    const int b = blockIdx.z;
    const int l0 = blockIdx.y * 128, col0 = blockIdx.x * 64;
    const int sr = t >> 3, sc = (t & 7) * 8;
    const unsigned short* Xb = X + (size_t)b * L * C;
    const int KWC = KW * C;
    f32x4 acc[2][4] = {};

    for (int kb = 0; kb < KW; ++kb) {
        for (int i0 = 0; i0 < C; i0 += 64) {
            __syncthreads();
#pragma unroll
            for (int p = 0; p < 4; ++p) {
                int r = p * 32 + sr;
                int row = l0 + r + kb; row = row < L ? row : L - 1;
                *(uint4*)&As[r][sc] = *(const uint4*)(Xb + (size_t)row * C + i0 + sc);
            }
#pragma unroll
            for (int p = 0; p < 2; ++p) {
                int r = p * 32 + sr;
                *(uint4*)&Bs[r][sc] = *(const uint4*)(Wt + (size_t)(col0 + r) * KWC + kb * C + i0 + sc);
            }
            __syncthreads();
#pragma unroll
            for (int kk = 0; kk < 2; ++kk) {
                short8 a0 = *(const short8*)&As[w * 32 + lr][kk * 32 + lk];
                short8 a1 = *(const short8*)&As[w * 32 + 16 + lr][kk * 32 + lk];
                short8 b0 = *(const short8*)&Bs[lr][kk * 32 + lk];
                short8 b1 = *(const short8*)&Bs[16 + lr][kk * 32 + lk];
                short8 b2 = *(const short8*)&Bs[32 + lr][kk * 32 + lk];
                short8 b3 = *(const short8*)&Bs[48 + lr][kk * 32 + lk];
                acc[0][0] = __builtin_amdgcn_mfma_f32_16x16x32_bf16(a0, b0, acc[0][0], 0, 0, 0);
                acc[0][1] = __builtin_amdgcn_mfma_f32_16x16x32_bf16(a0, b1, acc[0][1], 0, 0, 0);
                acc[0][2] = __builtin_amdgcn_mfma_f32_16x16x32_bf16(a0, b2, acc[0][2], 0, 0, 0);
                acc[0][3] = __builtin_amdgcn_mfma_f32_16x16x32_bf16(a0, b3, acc[0][3], 0, 0, 0);
                acc[1][0] = __builtin_amdgcn_mfma_f32_16x16x32_bf16(a1, b0, acc[1][0], 0, 0, 0);
                acc[1][1] = __builtin_amdgcn_mfma_f32_16x16x32_bf16(a1, b1, acc[1][1], 0, 0, 0);
                acc[1][2] = __builtin_amdgcn_mfma_f32_16x16x32_bf16(a1, b2, acc[1][2], 0, 0, 0);
                acc[1][3] = __builtin_amdgcn_mfma_f32_16x16x32_bf16(a1, b3, acc[1][3], 0, 0, 0);
            }
        }
    }
    const int rb = (l >> 4) * 4;
#pragma unroll
    for (int i = 0; i < 2; ++i)
#pragma unroll
        for (int j = 0; j < 4; ++j) {
            const int gcol = col0 + j * 16 + lr;
            const float bv = bias[gcol];
#pragma unroll
            for (int r = 0; r < 4; ++r) {
                const int grow = l0 + w * 32 + i * 16 + rb + r;
                if (grow < Lv)
                    Y[((size_t)b * Lv + grow) * N + gcol] = acc[i][j][r] + bv;
            }
        }
}

// ---------------- CSR gather aggregation ----------------
__global__ __launch_bounds__(64) void gather_agg(
    const unsigned short* __restrict__ Whb, const int* __restrict__ rowptr,
    const int* __restrict__ widx, unsigned short* __restrict__ aggb) {
    const int n = blockIdx.x, t = threadIdx.x;
    float a0 = 0, a1 = 0, a2 = 0, a3 = 0;
    const int s0 = rowptr[n], s1 = rowptr[n + 1];
    for (int s = s0; s < s1; ++s) {
        const ushort4 v = *(const ushort4*)(Whb + (size_t)widx[s] * 256 + t * 4);
        a0 += bf2f(v.x); a1 += bf2f(v.y); a2 += bf2f(v.z); a3 += bf2f(v.w);
    }
    ushort4 o; o.x = f2bf(a0); o.y = f2bf(a1); o.z = f2bf(a2); o.w = f2bf(a3);
    *(ushort4*)(aggb + (size_t)n * 256 + t * 4) = o;
}

// GRU cell update, in-place h (+ bf16 copy)
__global__ void gru_update(const float* __restrict__ gi, const float* __restrict__ gh,
                           float* __restrict__ h, unsigned short* __restrict__ hb) {
    int i = blockIdx.x * 256 + threadIdx.x;
    int n = i >> 8, k = i & 255;
    size_t base = (size_t)n * 768;
    float ir = gi[base + k], iz = gi[base + 256 + k], ig = gi[base + 512 + k];
    float hr = gh[base + k], hz = gh[base + 256 + k], hg = gh[base + 512 + k];
    float r  = 1.f / (1.f + expf(-(ir + hr)));
    float z  = 1.f / (1.f + expf(-(iz + hz)));
    float nn = tanhf(ig + r * hg);
    float hv = (1.f - z) * nn + z * h[i];
    h[i] = hv; hb[i] = f2bf(hv);
}

// ---------------- BN stats: parallel 2-level deterministic reduction ----------------
// Pass 1: grid (C/128, NCHUNK), block 256 = 32 ch-quads x 8 row-lanes; float4 loads.
// pS/pQ layout: [NCHUNK][C].
constexpr int NCHUNK = 128;
__global__ __launch_bounds__(256) void bn_part_cl(
    const float* __restrict__ X, float* __restrict__ pS, float* __restrict__ pQ,
    int C, int totalRows, int rowsPerChunk) {
    const int t  = threadIdx.x;
    const int cq = t & 31, rl = t >> 5;
    const int c0 = blockIdx.x * 128 + cq * 4;
    const int r0 = blockIdx.y * rowsPerChunk;
    const int r1 = min(r0 + rowsPerChunk, totalRows);
    float s0 = 0, s1 = 0, s2 = 0, s3 = 0, q0 = 0, q1 = 0, q2 = 0, q3 = 0;
    for (int r = r0 + rl; r < r1; r += 8) {
        float4 v = *(const float4*)(X + (size_t)r * C + c0);
        s0 += v.x; s1 += v.y; s2 += v.z; s3 += v.w;
        q0 += v.x * v.x; q1 += v.y * v.y; q2 += v.z * v.z; q3 += v.w * v.w;
    }
    __shared__ float ls[8][128], lq[8][128];
    ls[rl][cq * 4 + 0] = s0; ls[rl][cq * 4 + 1] = s1;
    ls[rl][cq * 4 + 2] = s2; ls[rl][cq * 4 + 3] = s3;
    lq[rl][cq * 4 + 0] = q0; lq[rl][cq * 4 + 1] = q1;
    lq[rl][cq * 4 + 2] = q2; lq[rl][cq * 4 + 3] = q3;
    __syncthreads();
    if (rl == 0) {
#pragma unroll
        for (int i = 0; i < 4; ++i) {
            const int c = cq * 4 + i;
            float ss = 0, qq = 0;
#pragma unroll
            for (int j = 0; j < 8; ++j) { ss += ls[j][c]; qq += lq[j][c]; }
            pS[(size_t)blockIdx.y * C + c0 + i] = ss;
            pQ[(size_t)blockIdx.y * C + c0 + i] = qq;
        }
    }
}

// Pass 2: one block per channel; 128-thread tree over NCHUNK partials.
__global__ __launch_bounds__(128) void bn_reduce_cl(
    const float* __restrict__ pS, const float* __restrict__ pQ,
    float* __restrict__ mean, float* __restrict__ var, int C, int totalRows) {
    const int c = blockIdx.x, t = threadIdx.x;
    __shared__ float rs[128], rq[128];
    rs[t] = pS[(size_t)t * C + c];
    rq[t] = pQ[(size_t)t * C + c];
    __syncthreads();
    for (int st = 64; st; st >>= 1) {
        if (t < st) { rs[t] += rs[t + st]; rq[t] += rq[t + st]; }
        __syncthreads();
    }
    if (t == 0) {
        float m = rs[0] / totalRows;
        mean[c] = m;
        var[c]  = rq[0] / totalRows - m * m;
    }
}

// ---------------- fused BN + ReLU + maxpool (channel-last) ----------------
__global__ void bnp_cl(const float* __restrict__ X, const float* __restrict__ mean,
                       const float* __restrict__ var, const float* __restrict__ g,
                       const float* __restrict__ bta, float* __restrict__ Of,
                       unsigned short* __restrict__ Ob, int C, int Lin, int Lout,
                       int Kp, int outBf) {
    int idx = blockIdx.x * 256 + threadIdx.x;
    if (idx >= Bn * Lout * C) return;
    int c = idx % C, j = (idx / C) % Lout, b = idx / (C * Lout);
    float sc = g[c] * rsqrtf(var[c] + 1e-5f);
    float sh = bta[c] - mean[c] * sc;
    const float* xb = X + ((size_t)b * Lin + j * 2) * C + c;
    float m = 0.f;
    for (int k = 0; k < Kp; ++k) m = fmaxf(m, xb[(size_t)k * C] * sc + sh);
    if (outBf) Ob[idx] = f2bf(m);
    else       Of[idx] = m;
}

// ---------------- final gating ----------------
__global__ void final_dot(const float* __restrict__ Y2, const float* __restrict__ Z2,
                          const float* __restrict__ wy, const float* __restrict__ by,
                          const float* __restrict__ wz, const float* __restrict__ bz,
                          float* __restrict__ prod) {
    const int b = blockIdx.y, j = blockIdx.x, t = threadIdx.x;
    float p0 = 0, p1 = 0, q0 = 0, q1 = 0;
    const float* yrow = Y2 + (size_t)(b * 255 + j) * FOUT;
    const float* zrow = Z2 + (size_t)(b * 255 + j) * CCAT;
    for (int c = t; c < FOUT; c += 128) {
        float v = yrow[c];
        p0 += v * wy[c]; p1 += v * wy[FOUT + c];
    }
    for (int c = t; c < CCAT; c += 128) {
        float v = zrow[c];
        q0 += v * wz[c]; q1 += v * wz[CCAT + c];
    }
    __shared__ float r0[128], r1[128], r2[128], r3[128];
    r0[t] = p0; r1[t] = p1; r2[t] = q0; r3[t] = q1;
    __syncthreads();
    for (int s = 64; s; s >>= 1) {
        if (t < s) { r0[t] += r0[t + s]; r1[t] += r1[t + s]; r2[t] += r2[t + s]; r3[t] += r3[t + s]; }
        __syncthreads();
    }
    if (t == 0) {
        float y0 = r0[0] + by[0], y1 = r1[0] + by[1];
        float z0 = r2[0] + bz[0], z1 = r3[0] + bz[1];
        prod[((size_t)b * 255 + j) * 2 + 0] = y0 * z0;
        prod[((size_t)b * 255 + j) * 2 + 1] = y1 * z1;
    }
}

__global__ void final_out(const float* __restrict__ prod, float* __restrict__ out) {
    const int b = blockIdx.x, t = threadIdx.x;
    const int w = t >> 6, lane = t & 63;
    float s = 0.f;
    for (int j = lane; j < 255; j += 64) s += prod[((size_t)b * 255 + j) * 2 + w];
#pragma unroll
    for (int off = 32; off; off >>= 1) s += __shfl_down(s, off);
    if (lane == 0) out[b * 2 + w] = 1.f / (1.f + expf(-s / 255.f));
}

// ---------------- launch ----------------
extern "C" void kernel_launch(void* const* d_in, const int* in_sizes, int n_in,
                              void* d_out, int out_size, void* d_ws, size_t ws_size,
                              hipStream_t stream) {
    (void)in_sizes; (void)n_in; (void)out_size; (void)ws_size;
    const float* features = (const float*)d_in[0];
    const int*   src      = (const int*)d_in[1];
    const int*   dst      = (const int*)d_in[2];
    const int*   etype    = (const int*)d_in[3];
    const float* W_lin    = (const float*)d_in[4];
    const float* b_lin    = (const float*)d_in[5];
    const float* W_ih     = (const float*)d_in[6];
    const float* W_hh     = (const float*)d_in[7];
    const float* b_ih     = (const float*)d_in[8];
    const float* b_hh     = (const float*)d_in[9];
    const float* conv1_w  = (const float*)d_in[10];
    const float* conv1_b  = (const float*)d_in[11];
    const float* conv2_w  = (const float*)d_in[12];
    const float* conv2_b  = (const float*)d_in[13];
    const float* convc1_w = (const float*)d_in[14];
    const float* convc1_b = (const float*)d_in[15];
    const float* convc2_w = (const float*)d_in[16];
    const float* convc2_b = (const float*)d_in[17];
    const float* bn_g     = (const float*)d_in[18];
    const float* bn_b     = (const float*)d_in[19];
    const float* bnc_g    = (const float*)d_in[20];
    const float* bnc_b    = (const float*)d_in[21];
    const float* mlpy_w   = (const float*)d_in[22];
    const float* mlpy_b   = (const float*)d_in[23];
    const float* mlpz_w   = (const float*)d_in[24];
    const float* mlpz_b   = (const float*)d_in[25];

    float* ws = (float*)d_ws;
    // ---- GGNN-phase layout (float offsets) ----
    float*          h    = ws;                                   // 4,194,304 f
    unsigned short* hb   = (unsigned short*)(ws + 4194304);      // 2,097,152 f-slots
    unsigned short* aggb = (unsigned short*)(ws + 6291456);      // 2,097,152 f-slots
    float*          bufA = ws + 8388608;                         // 12,582,912 f
    float*          bufB = ws + 20971520;                        // 12,582,912 f
    unsigned short* Wb   = (unsigned short*)(ws + 33554432);     // 262,144 f-slots
    int*            ib   = (int*)(ws + 33825536);                // CSR ints
    int* deg    = ib;
    int* cursor = ib + 16384;
    int* rowptr = ib + 32768;
    int* widx   = ib + 49160;

    unsigned short* Wlin_b = Wb;               // [512][256]
    unsigned short* Wih_b  = Wb + 131072;      // [768][256]
    unsigned short* Whh_b  = Wb + 327680;      // [768][256]
    unsigned short* Whb    = (unsigned short*)bufA;  // [16384][512] bf16

    // ---- weight conversion + CSR build ----
    cvt_bf<<<512,  256, 0, stream>>>(W_lin, Wlin_b, 131072);
    cvt_bf<<<768,  256, 0, stream>>>(W_ih,  Wih_b,  196608);
    cvt_bf<<<768,  256, 0, stream>>>(W_hh,  Whh_b,  196608);
    pad_h<<<Nn * FOUT / 256, 256, 0, stream>>>(features, h, hb);

    hipMemsetAsync(deg, 0, 16384 * sizeof(int), stream);
    edge_count<<<NE / 256, 256, 0, stream>>>(dst, deg);
    scan_deg<<<1, 1024, 0, stream>>>(deg, rowptr, cursor);
    edge_fill<<<NE / 256, 256, 0, stream>>>(src, dst, etype, cursor, widx);

    // ---- GGNN steps ----
    for (int s6 = 0; s6 < STEPS; ++s6) {
        gemm_mfma<<<dim3(512 / 64, Nn / 128), 256, 0, stream>>>(
            hb, Wlin_b, b_lin, nullptr, Whb, 512, 1);
        gather_agg<<<Nn, 64, 0, stream>>>(Whb, rowptr, widx, aggb);
        gemm_mfma<<<dim3(768 / 64, Nn / 128), 256, 0, stream>>>(
            hb, Whh_b, b_hh, bufB, nullptr, 768, 0);
        gemm_mfma<<<dim3(768 / 64, Nn / 128), 256, 0, stream>>>(
            aggb, Wih_b, b_ih, bufA, nullptr, 768, 0);
        gru_update<<<Nn * FOUT / 256, 256, 0, stream>>>(bufA, bufB, h, hb);
    }

    // ---- conv-phase layout (channel-last) ----
    unsigned short* cb    = (unsigned short*)ws;                 // [16384][384] bf16
    float*          Yc1   = bufA;                                // [16352][256] f32
    unsigned short* P1y   = (unsigned short*)(bufA + 4186112);   // [8160][256] bf16
    float*          Yc2   = bufA + 5230592;                      // [8160][256] f32
    float*          Y2    = bufA + 7319552;                      // [4080][256] f32
    float*          Z2    = bufA + 8364032;                      // [4080][384] f32
    float*          Zc1   = bufB;                                // [16352][384] f32
    unsigned short* P1z   = (unsigned short*)(bufB + 6279168);   // [8160][384] bf16
    float*          Zc2   = bufB + 7845888;                      // [8160][384] f32
    unsigned short* Wcv   = (unsigned short*)(bufB + 11000000);  // conv weights bf16
    unsigned short* c1b   = Wcv;                                 // [256][768]
    unsigned short* c2b   = Wcv + 196608;                        // [256][256]
    unsigned short* cc1b  = Wcv + 262144;                        // [384][1152]
    unsigned short* cc2b  = Wcv + 704512;                        // [384][384]
    float* sreg  = (float*)aggb;                                 // stats region (aggb dead)
    float* meanb = sreg;             // 384
    float* varb  = sreg + 384;       // 384
    float* pS    = sreg + 1024;      // NCHUNK*384 = 49152
    float* pQ    = sreg + 50176;     // NCHUNK*384
    float* prod  = sreg + 99328;     // [16][255][2]

    cvt_wconv<<<768,  256, 0, stream>>>(conv1_w,  c1b,  FOUT, 3, FOUT * FOUT * 3);
    cvt_wconv<<<256,  256, 0, stream>>>(conv2_w,  c2b,  FOUT, 1, FOUT * FOUT);
    cvt_wconv<<<1728, 256, 0, stream>>>(convc1_w, cc1b, CCAT, 3, CCAT * CCAT * 3);
    cvt_wconv<<<576,  256, 0, stream>>>(convc2_w, cc2b, CCAT, 1, CCAT * CCAT);
    build_cb<<<Nn * CCAT / 256, 256, 0, stream>>>(hb, features, cb);

    const int rows1 = Bn * 1022;   // 16352
    const int rows2 = Bn * 510;    // 8160
    const int rpc1  = (rows1 + NCHUNK - 1) / NCHUNK;   // 128
    const int rpc2  = (rows2 + NCHUNK - 1) / NCHUNK;   // 64

    // ---- Y branch ----
    conv_mfma<3><<<dim3(4, 8, Bn), 256, 0, stream>>>(hb, c1b, conv1_b, Yc1, FOUT, 1024, 1022, FOUT);
    bn_part_cl<<<dim3(FOUT / 128, NCHUNK), 256, 0, stream>>>(Yc1, pS, pQ, FOUT, rows1, rpc1);
    bn_reduce_cl<<<FOUT, 128, 0, stream>>>(pS, pQ, meanb, varb, FOUT, rows1);
    bnp_cl<<<(Bn * 510 * FOUT + 255) / 256, 256, 0, stream>>>(
        Yc1, meanb, varb, bn_g, bn_b, nullptr, P1y, FOUT, 1022, 510, 3, 1);
    conv_mfma<1><<<dim3(4, 4, Bn), 256, 0, stream>>>(P1y, c2b, conv2_b, Yc2, FOUT, 510, 510, FOUT);
    bn_part_cl<<<dim3(FOUT / 128, NCHUNK), 256, 0, stream>>>(Yc2, pS, pQ, FOUT, rows2, rpc2);
    bn_reduce_cl<<<FOUT, 128, 0, stream>>>(pS, pQ, meanb, varb, FOUT, rows2);
    bnp_cl<<<(Bn * 255 * FOUT + 255) / 256, 256, 0, stream>>>(
        Yc2, meanb, varb, bn_g, bn_b, Y2, nullptr, FOUT, 510, 255, 2, 0);

    // ---- Z branch ----
    conv_mfma<3><<<dim3(6, 8, Bn), 256, 0, stream>>>(cb, cc1b, convc1_b, Zc1, CCAT, 1024, 1022, CCAT);
    bn_part_cl<<<dim3(CCAT / 128, NCHUNK), 256, 0, stream>>>(Zc1, pS, pQ, CCAT, rows1, rpc1);
    bn_reduce_cl<<<CCAT, 128, 0, stream>>>(pS, pQ, meanb, varb, CCAT, rows1);
    bnp_cl<<<(Bn * 510 * CCAT + 255) / 256, 256, 0, stream>>>(
        Zc1, meanb, varb, bnc_g, bnc_b, nullptr, P1z, CCAT, 1022, 510, 3, 1);
    conv_mfma<1><<<dim3(6, 4, Bn), 256, 0, stream>>>(P1z, cc2b, convc2_b, Zc2, CCAT, 510, 510, CCAT);
    bn_part_cl<<<dim3(CCAT / 128, NCHUNK), 256, 0, stream>>>(Zc2, pS, pQ, CCAT, rows2, rpc2);
    bn_reduce_cl<<<CCAT, 128, 0, stream>>>(pS, pQ, meanb, varb, CCAT, rows2);
    bnp_cl<<<(Bn * 255 * CCAT + 255) / 256, 256, 0, stream>>>(
        Zc2, meanb, varb, bnc_g, bnc_b, Z2, nullptr, CCAT, 510, 255, 2, 0);

    // ---- gating + mean + sigmoid ----
    final_dot<<<dim3(255, Bn), 128, 0, stream>>>(Y2, Z2, mlpy_w, mlpy_b, mlpz_w, mlpz_b, prod);
    final_out<<<Bn, 128, 0, stream>>>(prod, (float*)d_out);
}